// Round 1
// baseline (1140.793 us; speedup 1.0000x reference)
//
#include <hip/hip_runtime.h>
#include <hip/hip_bf16.h>

#define N_NODES 50000
#define N_EDGES 800000
#define NFEAT 256
#define NHID 128
#define LATENT 64

typedef __attribute__((ext_vector_type(8))) short bf16x8;
typedef __attribute__((ext_vector_type(4))) float f32x4;
typedef __attribute__((ext_vector_type(4))) short short4v;

__device__ inline short f2bf(float f) {
  union { float f; unsigned u; } c; c.f = f;
  unsigned r = (c.u + 0x7FFFu + ((c.u >> 16) & 1u)) >> 16;
  return (short)r;
}

// ---------------------------------------------------------------------------
// GEMM1: XW[M=50000][128] = x[M][256] @ W1[256][128]   (bf16 MFMA, fp32 out)
// 128x128 tile per block, 256 threads = 4 waves in 2x2, each wave 64x64.
// ---------------------------------------------------------------------------
__launch_bounds__(256)
__global__ void gemm1_kernel(const float* __restrict__ X,
                             const float* __restrict__ W1,
                             float* __restrict__ XW) {
  __shared__ short A_lds[128][40];  // [row][k] padded +8 to break conflicts
  __shared__ short B_lds[128][40];  // [n][k]   (B transposed into LDS)
  const int t = threadIdx.x;
  const int lane = t & 63;
  const int wave = t >> 6;
  const int wm = wave >> 1, wn = wave & 1;
  const int row0 = blockIdx.x * 128;
  const int l15 = lane & 15, quad = lane >> 4;

  f32x4 acc[4][4];
#pragma unroll
  for (int i = 0; i < 4; i++)
#pragma unroll
    for (int j = 0; j < 4; j++) acc[i][j] = (f32x4){0.f, 0.f, 0.f, 0.f};

  for (int k0 = 0; k0 < NFEAT; k0 += 32) {
    // stage A: 128 rows x 32 cols, fp32 -> bf16
#pragma unroll
    for (int r = 0; r < 4; r++) {
      int i = t + 256 * r;
      int ar = i >> 3, grp = i & 7;
      int gr = row0 + ar;
      float4 v = (gr < N_NODES)
                     ? *(const float4*)(X + (size_t)gr * NFEAT + k0 + grp * 4)
                     : make_float4(0.f, 0.f, 0.f, 0.f);
      short4v s;
      s.x = f2bf(v.x); s.y = f2bf(v.y); s.z = f2bf(v.z); s.w = f2bf(v.w);
      *(short4v*)&A_lds[ar][grp * 4] = s;
    }
    // stage B transposed: B_lds[n][kk] = W1[k0+kk][n]
#pragma unroll
    for (int r = 0; r < 4; r++) {
      int i = t + 256 * r;
      int kr = i >> 5, grp = i & 31;
      float4 v = *(const float4*)(W1 + (size_t)(k0 + kr) * NHID + grp * 4);
      B_lds[grp * 4 + 0][kr] = f2bf(v.x);
      B_lds[grp * 4 + 1][kr] = f2bf(v.y);
      B_lds[grp * 4 + 2][kr] = f2bf(v.z);
      B_lds[grp * 4 + 3][kr] = f2bf(v.w);
    }
    __syncthreads();
    bf16x8 a[4], b[4];
#pragma unroll
    for (int mt = 0; mt < 4; mt++)
      a[mt] = *(const bf16x8*)&A_lds[wm * 64 + mt * 16 + l15][quad * 8];
#pragma unroll
    for (int nt = 0; nt < 4; nt++)
      b[nt] = *(const bf16x8*)&B_lds[wn * 64 + nt * 16 + l15][quad * 8];
#pragma unroll
    for (int mt = 0; mt < 4; mt++)
#pragma unroll
      for (int nt = 0; nt < 4; nt++)
        acc[mt][nt] = __builtin_amdgcn_mfma_f32_16x16x32_bf16(a[mt], b[nt], acc[mt][nt], 0, 0, 0);
    __syncthreads();
  }
  // epilogue: C row = quad*4+reg, col = l15 (verified m89/m91 layout)
#pragma unroll
  for (int mt = 0; mt < 4; mt++) {
#pragma unroll
    for (int reg = 0; reg < 4; reg++) {
      int gr = row0 + wm * 64 + mt * 16 + quad * 4 + reg;
      if (gr < N_NODES) {
#pragma unroll
        for (int nt = 0; nt < 4; nt++) {
          int gc = wn * 64 + nt * 16 + l15;
          XW[(size_t)gr * NHID + gc] = acc[mt][nt][reg];
        }
      }
    }
  }
}

// ---------------------------------------------------------------------------
// GEMM2: T[M][128] = relu(agg1[M][128] + b1) @ concat(Wmu|Wlv)[128][128]
// bias+relu fused into A-staging.
// ---------------------------------------------------------------------------
__launch_bounds__(256)
__global__ void gemm2_kernel(const float* __restrict__ AGG,
                             const float* __restrict__ b1,
                             const float* __restrict__ Wmu,
                             const float* __restrict__ Wlv,
                             float* __restrict__ T) {
  __shared__ short A_lds[128][40];
  __shared__ short B_lds[128][40];
  const int t = threadIdx.x;
  const int lane = t & 63;
  const int wave = t >> 6;
  const int wm = wave >> 1, wn = wave & 1;
  const int row0 = blockIdx.x * 128;
  const int l15 = lane & 15, quad = lane >> 4;

  f32x4 acc[4][4];
#pragma unroll
  for (int i = 0; i < 4; i++)
#pragma unroll
    for (int j = 0; j < 4; j++) acc[i][j] = (f32x4){0.f, 0.f, 0.f, 0.f};

  for (int k0 = 0; k0 < NHID; k0 += 32) {
#pragma unroll
    for (int r = 0; r < 4; r++) {
      int i = t + 256 * r;
      int ar = i >> 3, grp = i & 7;
      int gr = row0 + ar;
      float4 bb = *(const float4*)(b1 + k0 + grp * 4);
      float4 v = (gr < N_NODES)
                     ? *(const float4*)(AGG + (size_t)gr * NHID + k0 + grp * 4)
                     : make_float4(0.f, 0.f, 0.f, 0.f);
      v.x = fmaxf(v.x + bb.x, 0.f);
      v.y = fmaxf(v.y + bb.y, 0.f);
      v.z = fmaxf(v.z + bb.z, 0.f);
      v.w = fmaxf(v.w + bb.w, 0.f);
      if (gr >= N_NODES) { v = make_float4(0.f, 0.f, 0.f, 0.f); }
      short4v s;
      s.x = f2bf(v.x); s.y = f2bf(v.y); s.z = f2bf(v.z); s.w = f2bf(v.w);
      *(short4v*)&A_lds[ar][grp * 4] = s;
    }
    // B rows k0..k0+31 of concat(Wmu|Wlv): n = grp*4+j works for both halves
#pragma unroll
    for (int r = 0; r < 4; r++) {
      int i = t + 256 * r;
      int kr = i >> 5, grp = i & 31;
      const float* Wp = (grp < 16) ? (Wmu + (size_t)(k0 + kr) * LATENT + grp * 4)
                                   : (Wlv + (size_t)(k0 + kr) * LATENT + (grp - 16) * 4);
      float4 v = *(const float4*)Wp;
      B_lds[grp * 4 + 0][kr] = f2bf(v.x);
      B_lds[grp * 4 + 1][kr] = f2bf(v.y);
      B_lds[grp * 4 + 2][kr] = f2bf(v.z);
      B_lds[grp * 4 + 3][kr] = f2bf(v.w);
    }
    __syncthreads();
    bf16x8 a[4], b[4];
#pragma unroll
    for (int mt = 0; mt < 4; mt++)
      a[mt] = *(const bf16x8*)&A_lds[wm * 64 + mt * 16 + l15][quad * 8];
#pragma unroll
    for (int nt = 0; nt < 4; nt++)
      b[nt] = *(const bf16x8*)&B_lds[wn * 64 + nt * 16 + l15][quad * 8];
#pragma unroll
    for (int mt = 0; mt < 4; mt++)
#pragma unroll
      for (int nt = 0; nt < 4; nt++)
        acc[mt][nt] = __builtin_amdgcn_mfma_f32_16x16x32_bf16(a[mt], b[nt], acc[mt][nt], 0, 0, 0);
    __syncthreads();
  }
#pragma unroll
  for (int mt = 0; mt < 4; mt++) {
#pragma unroll
    for (int reg = 0; reg < 4; reg++) {
      int gr = row0 + wm * 64 + mt * 16 + quad * 4 + reg;
      if (gr < N_NODES) {
#pragma unroll
        for (int nt = 0; nt < 4; nt++) {
          int gc = wn * 64 + nt * 16 + l15;
          T[(size_t)gr * NHID + gc] = acc[mt][nt][reg];
        }
      }
    }
  }
}

// ---------------------------------------------------------------------------
// Scatter 1: agg[dst[e]][:] += XW[src[e]][:] * ew[e]   (one wave per edge)
// ---------------------------------------------------------------------------
__launch_bounds__(256)
__global__ void scatter1_kernel(const float* __restrict__ XW,
                                const int* __restrict__ src,
                                const int* __restrict__ dst,
                                const float* __restrict__ ew,
                                float* __restrict__ agg) {
  int gw = (int)((blockIdx.x * blockDim.x + threadIdx.x) >> 6);
  if (gw >= N_EDGES) return;
  int lane = threadIdx.x & 63;
  int s = src[gw], d = dst[gw];
  float w = ew[gw];
  float2 v = *(const float2*)(XW + (size_t)s * NHID + lane * 2);
  float* dp = agg + (size_t)d * NHID + lane * 2;
  atomicAdd(dp, v.x * w);
  atomicAdd(dp + 1, v.y * w);
}

// ---------------------------------------------------------------------------
// Scatter 2: out_mu[dst] += T[src][0:64]*w ; out_lv[dst] += T[src][64:128]*w
// ---------------------------------------------------------------------------
__launch_bounds__(256)
__global__ void scatter2_kernel(const float* __restrict__ T,
                                const int* __restrict__ src,
                                const int* __restrict__ dst,
                                const float* __restrict__ ew,
                                float* __restrict__ out) {
  int gw = (int)((blockIdx.x * blockDim.x + threadIdx.x) >> 6);
  if (gw >= N_EDGES) return;
  int lane = threadIdx.x & 63;
  int s = src[gw], d = dst[gw];
  float w = ew[gw];
  float vmu = T[(size_t)s * NHID + lane];
  float vlv = T[(size_t)s * NHID + 64 + lane];
  atomicAdd(out + (size_t)d * LATENT + lane, vmu * w);
  atomicAdd(out + (size_t)N_NODES * LATENT + (size_t)d * LATENT + lane, vlv * w);
}

// ---------------------------------------------------------------------------
// Init output with biases (d_out is poisoned 0xAA before every launch)
// ---------------------------------------------------------------------------
__launch_bounds__(256)
__global__ void init_out_kernel(float* __restrict__ out,
                                const float* __restrict__ bmu,
                                const float* __restrict__ blv) {
  int idx = blockIdx.x * 256 + threadIdx.x;
  if (idx >= 2 * N_NODES * LATENT) return;
  int f = idx & 63;
  out[idx] = (idx < N_NODES * LATENT) ? bmu[f] : blv[f];
}

extern "C" void kernel_launch(void* const* d_in, const int* in_sizes, int n_in,
                              void* d_out, int out_size, void* d_ws, size_t ws_size,
                              hipStream_t stream) {
  const float* x   = (const float*)d_in[0];
  const int*   src = (const int*)d_in[1];
  const int*   dst = (const int*)d_in[2];
  const float* ew  = (const float*)d_in[3];
  const float* W1  = (const float*)d_in[4];
  const float* b1  = (const float*)d_in[5];
  const float* Wmu = (const float*)d_in[6];
  const float* bmu = (const float*)d_in[7];
  const float* Wlv = (const float*)d_in[8];
  const float* blv = (const float*)d_in[9];
  float* out = (float*)d_out;

  float* buf0 = (float*)d_ws;                         // XW, later T (50000*128 f32)
  float* buf1 = buf0 + (size_t)N_NODES * NHID;        // agg1       (50000*128 f32)

  hipMemsetAsync(buf1, 0, (size_t)N_NODES * NHID * sizeof(float), stream);

  dim3 blk(256);
  int gemm_grid = (N_NODES + 127) / 128;  // 391

  gemm1_kernel<<<gemm_grid, blk, 0, stream>>>(x, W1, buf0);
  scatter1_kernel<<<(N_EDGES + 3) / 4, blk, 0, stream>>>(buf0, src, dst, ew, buf1);
  init_out_kernel<<<(2 * N_NODES * LATENT + 255) / 256, blk, 0, stream>>>(out, bmu, blv);
  gemm2_kernel<<<gemm_grid, blk, 0, stream>>>(buf1, b1, Wmu, Wlv, buf0);
  scatter2_kernel<<<(N_EDGES + 3) / 4, blk, 0, stream>>>(buf0, src, dst, ew, out);
}

// Round 2
// 418.395 us; speedup vs baseline: 2.7266x; 2.7266x over previous
//
#include <hip/hip_runtime.h>
#include <hip/hip_bf16.h>

#define N_NODES 50000
#define N_EDGES 800000
#define NFEAT 256
#define NHID 128
#define LATENT 64
#define SCAN_BLOCKS 196  // ceil(50000/256)

typedef __attribute__((ext_vector_type(8))) short bf16x8;
typedef __attribute__((ext_vector_type(4))) float f32x4;
typedef __attribute__((ext_vector_type(4))) short short4v;

__device__ inline short f2bf(float f) {
  union { float f; unsigned u; } c; c.f = f;
  unsigned r = (c.u + 0x7FFFu + ((c.u >> 16) & 1u)) >> 16;
  return (short)r;
}

// ---------------------------------------------------------------------------
// GEMM1: XW[M=50000][128] = x[M][256] @ W1[256][128]   (bf16 MFMA, fp32 out)
// ---------------------------------------------------------------------------
__launch_bounds__(256)
__global__ void gemm1_kernel(const float* __restrict__ X,
                             const float* __restrict__ W1,
                             float* __restrict__ XW) {
  __shared__ short A_lds[128][40];
  __shared__ short B_lds[128][40];
  const int t = threadIdx.x;
  const int lane = t & 63;
  const int wave = t >> 6;
  const int wm = wave >> 1, wn = wave & 1;
  const int row0 = blockIdx.x * 128;
  const int l15 = lane & 15, quad = lane >> 4;

  f32x4 acc[4][4];
#pragma unroll
  for (int i = 0; i < 4; i++)
#pragma unroll
    for (int j = 0; j < 4; j++) acc[i][j] = (f32x4){0.f, 0.f, 0.f, 0.f};

  for (int k0 = 0; k0 < NFEAT; k0 += 32) {
#pragma unroll
    for (int r = 0; r < 4; r++) {
      int i = t + 256 * r;
      int ar = i >> 3, grp = i & 7;
      int gr = row0 + ar;
      float4 v = (gr < N_NODES)
                     ? *(const float4*)(X + (size_t)gr * NFEAT + k0 + grp * 4)
                     : make_float4(0.f, 0.f, 0.f, 0.f);
      short4v s;
      s.x = f2bf(v.x); s.y = f2bf(v.y); s.z = f2bf(v.z); s.w = f2bf(v.w);
      *(short4v*)&A_lds[ar][grp * 4] = s;
    }
#pragma unroll
    for (int r = 0; r < 4; r++) {
      int i = t + 256 * r;
      int kr = i >> 5, grp = i & 31;
      float4 v = *(const float4*)(W1 + (size_t)(k0 + kr) * NHID + grp * 4);
      B_lds[grp * 4 + 0][kr] = f2bf(v.x);
      B_lds[grp * 4 + 1][kr] = f2bf(v.y);
      B_lds[grp * 4 + 2][kr] = f2bf(v.z);
      B_lds[grp * 4 + 3][kr] = f2bf(v.w);
    }
    __syncthreads();
    bf16x8 a[4], b[4];
#pragma unroll
    for (int mt = 0; mt < 4; mt++)
      a[mt] = *(const bf16x8*)&A_lds[wm * 64 + mt * 16 + l15][quad * 8];
#pragma unroll
    for (int nt = 0; nt < 4; nt++)
      b[nt] = *(const bf16x8*)&B_lds[wn * 64 + nt * 16 + l15][quad * 8];
#pragma unroll
    for (int mt = 0; mt < 4; mt++)
#pragma unroll
      for (int nt = 0; nt < 4; nt++)
        acc[mt][nt] = __builtin_amdgcn_mfma_f32_16x16x32_bf16(a[mt], b[nt], acc[mt][nt], 0, 0, 0);
    __syncthreads();
  }
#pragma unroll
  for (int mt = 0; mt < 4; mt++) {
#pragma unroll
    for (int reg = 0; reg < 4; reg++) {
      int gr = row0 + wm * 64 + mt * 16 + quad * 4 + reg;
      if (gr < N_NODES) {
#pragma unroll
        for (int nt = 0; nt < 4; nt++) {
          int gc = wn * 64 + nt * 16 + l15;
          XW[(size_t)gr * NHID + gc] = acc[mt][nt][reg];
        }
      }
    }
  }
}

// ---------------------------------------------------------------------------
// GEMM2: T[M][128] = relu(agg1[M][128] + b1) @ concat(Wmu|Wlv)[128][128]
// ---------------------------------------------------------------------------
__launch_bounds__(256)
__global__ void gemm2_kernel(const float* __restrict__ AGG,
                             const float* __restrict__ b1,
                             const float* __restrict__ Wmu,
                             const float* __restrict__ Wlv,
                             float* __restrict__ T) {
  __shared__ short A_lds[128][40];
  __shared__ short B_lds[128][40];
  const int t = threadIdx.x;
  const int lane = t & 63;
  const int wave = t >> 6;
  const int wm = wave >> 1, wn = wave & 1;
  const int row0 = blockIdx.x * 128;
  const int l15 = lane & 15, quad = lane >> 4;

  f32x4 acc[4][4];
#pragma unroll
  for (int i = 0; i < 4; i++)
#pragma unroll
    for (int j = 0; j < 4; j++) acc[i][j] = (f32x4){0.f, 0.f, 0.f, 0.f};

  for (int k0 = 0; k0 < NHID; k0 += 32) {
#pragma unroll
    for (int r = 0; r < 4; r++) {
      int i = t + 256 * r;
      int ar = i >> 3, grp = i & 7;
      int gr = row0 + ar;
      float4 bb = *(const float4*)(b1 + k0 + grp * 4);
      float4 v = (gr < N_NODES)
                     ? *(const float4*)(AGG + (size_t)gr * NHID + k0 + grp * 4)
                     : make_float4(0.f, 0.f, 0.f, 0.f);
      v.x = fmaxf(v.x + bb.x, 0.f);
      v.y = fmaxf(v.y + bb.y, 0.f);
      v.z = fmaxf(v.z + bb.z, 0.f);
      v.w = fmaxf(v.w + bb.w, 0.f);
      if (gr >= N_NODES) { v = make_float4(0.f, 0.f, 0.f, 0.f); }
      short4v s;
      s.x = f2bf(v.x); s.y = f2bf(v.y); s.z = f2bf(v.z); s.w = f2bf(v.w);
      *(short4v*)&A_lds[ar][grp * 4] = s;
    }
#pragma unroll
    for (int r = 0; r < 4; r++) {
      int i = t + 256 * r;
      int kr = i >> 5, grp = i & 31;
      const float* Wp = (grp < 16) ? (Wmu + (size_t)(k0 + kr) * LATENT + grp * 4)
                                   : (Wlv + (size_t)(k0 + kr) * LATENT + (grp - 16) * 4);
      float4 v = *(const float4*)Wp;
      B_lds[grp * 4 + 0][kr] = f2bf(v.x);
      B_lds[grp * 4 + 1][kr] = f2bf(v.y);
      B_lds[grp * 4 + 2][kr] = f2bf(v.z);
      B_lds[grp * 4 + 3][kr] = f2bf(v.w);
    }
    __syncthreads();
    bf16x8 a[4], b[4];
#pragma unroll
    for (int mt = 0; mt < 4; mt++)
      a[mt] = *(const bf16x8*)&A_lds[wm * 64 + mt * 16 + l15][quad * 8];
#pragma unroll
    for (int nt = 0; nt < 4; nt++)
      b[nt] = *(const bf16x8*)&B_lds[wn * 64 + nt * 16 + l15][quad * 8];
#pragma unroll
    for (int mt = 0; mt < 4; mt++)
#pragma unroll
      for (int nt = 0; nt < 4; nt++)
        acc[mt][nt] = __builtin_amdgcn_mfma_f32_16x16x32_bf16(a[mt], b[nt], acc[mt][nt], 0, 0, 0);
    __syncthreads();
  }
#pragma unroll
  for (int mt = 0; mt < 4; mt++) {
#pragma unroll
    for (int reg = 0; reg < 4; reg++) {
      int gr = row0 + wm * 64 + mt * 16 + quad * 4 + reg;
      if (gr < N_NODES) {
#pragma unroll
        for (int nt = 0; nt < 4; nt++) {
          int gc = wn * 64 + nt * 16 + l15;
          T[(size_t)gr * NHID + gc] = acc[mt][nt][reg];
        }
      }
    }
  }
}

// ---------------------------------------------------------------------------
// CSR build: histogram -> block scan -> bsum scan -> add offsets -> fill
// ---------------------------------------------------------------------------
__launch_bounds__(256)
__global__ void hist_kernel(const int* __restrict__ dst, int* __restrict__ cnt) {
  int e = blockIdx.x * 256 + threadIdx.x;
  if (e < N_EDGES) atomicAdd(&cnt[dst[e]], 1);
}

__launch_bounds__(256)
__global__ void scan_blocks_kernel(const int* __restrict__ cnt,
                                   int* __restrict__ partial,
                                   int* __restrict__ bsum) {
  __shared__ int lds[256];
  int t = threadIdx.x;
  int i = blockIdx.x * 256 + t;
  int v = (i < N_NODES) ? cnt[i] : 0;
  lds[t] = v;
  __syncthreads();
  int x = v;
  for (int ofs = 1; ofs < 256; ofs <<= 1) {
    int y = (t >= ofs) ? lds[t - ofs] : 0;
    __syncthreads();
    x += y;
    lds[t] = x;
    __syncthreads();
  }
  if (i < N_NODES) partial[i] = x - v;  // exclusive within block
  if (t == 255) bsum[blockIdx.x] = x;   // block total
}

__launch_bounds__(256)
__global__ void scan_bsums_kernel(int* __restrict__ bsum) {
  __shared__ int lds[256];
  int t = threadIdx.x;
  int v = (t < SCAN_BLOCKS) ? bsum[t] : 0;
  lds[t] = v;
  __syncthreads();
  int x = v;
  for (int ofs = 1; ofs < 256; ofs <<= 1) {
    int y = (t >= ofs) ? lds[t - ofs] : 0;
    __syncthreads();
    x += y;
    lds[t] = x;
    __syncthreads();
  }
  if (t < SCAN_BLOCKS) bsum[t] = x - v;  // exclusive over block totals
}

__launch_bounds__(256)
__global__ void add_offsets_kernel(const int* __restrict__ partial,
                                   const int* __restrict__ bsum,
                                   int* __restrict__ off,
                                   int* __restrict__ cursor) {
  int i = blockIdx.x * 256 + threadIdx.x;
  if (i < N_NODES) {
    int o = partial[i] + bsum[blockIdx.x];
    off[i] = o;
    cursor[i] = o;
  }
  if (i == 0) off[N_NODES] = N_EDGES;
}

__launch_bounds__(256)
__global__ void fill_kernel(const int* __restrict__ src,
                            const int* __restrict__ dst,
                            const float* __restrict__ ew,
                            int* __restrict__ cursor,
                            int2* __restrict__ edata) {
  int e = blockIdx.x * 256 + threadIdx.x;
  if (e < N_EDGES) {
    int pos = atomicAdd(&cursor[dst[e]], 1);
    edata[pos] = make_int2(src[e], __float_as_int(ew[e]));
  }
}

// ---------------------------------------------------------------------------
// Gather 1: agg[n][:] = sum_{j in CSR[n]} XW[src_j][:] * w_j   (no atomics)
// one wave per node; lane covers 2 feats (float2)
// ---------------------------------------------------------------------------
__launch_bounds__(256)
__global__ void gather1_kernel(const float* __restrict__ XW,
                               const int* __restrict__ off,
                               const int2* __restrict__ edata,
                               float* __restrict__ agg) {
  int gw = (int)((blockIdx.x * blockDim.x + threadIdx.x) >> 6);
  if (gw >= N_NODES) return;
  int lane = threadIdx.x & 63;
  int beg = off[gw], end = off[gw + 1];
  float ax = 0.f, ay = 0.f;
  for (int j = beg; j < end; j++) {
    int2 ed = edata[j];  // wave-uniform -> scalar load
    float w = __int_as_float(ed.y);
    float2 v = *(const float2*)(XW + (size_t)ed.x * NHID + lane * 2);
    ax += v.x * w;
    ay += v.y * w;
  }
  float2 o; o.x = ax; o.y = ay;
  *(float2*)(agg + (size_t)gw * NHID + lane * 2) = o;
}

// ---------------------------------------------------------------------------
// Gather 2: out_mu[n] = bmu + sum T[src][0:64]*w ; out_lv likewise
// ---------------------------------------------------------------------------
__launch_bounds__(256)
__global__ void gather2_kernel(const float* __restrict__ T,
                               const int* __restrict__ off,
                               const int2* __restrict__ edata,
                               const float* __restrict__ bmu,
                               const float* __restrict__ blv,
                               float* __restrict__ out) {
  int gw = (int)((blockIdx.x * blockDim.x + threadIdx.x) >> 6);
  if (gw >= N_NODES) return;
  int lane = threadIdx.x & 63;
  int beg = off[gw], end = off[gw + 1];
  float amu = 0.f, alv = 0.f;
  for (int j = beg; j < end; j++) {
    int2 ed = edata[j];
    float w = __int_as_float(ed.y);
    amu += T[(size_t)ed.x * NHID + lane] * w;
    alv += T[(size_t)ed.x * NHID + 64 + lane] * w;
  }
  out[(size_t)gw * LATENT + lane] = amu + bmu[lane];
  out[(size_t)N_NODES * LATENT + (size_t)gw * LATENT + lane] = alv + blv[lane];
}

extern "C" void kernel_launch(void* const* d_in, const int* in_sizes, int n_in,
                              void* d_out, int out_size, void* d_ws, size_t ws_size,
                              hipStream_t stream) {
  const float* x   = (const float*)d_in[0];
  const int*   src = (const int*)d_in[1];
  const int*   dst = (const int*)d_in[2];
  const float* ew  = (const float*)d_in[3];
  const float* W1  = (const float*)d_in[4];
  const float* b1  = (const float*)d_in[5];
  const float* Wmu = (const float*)d_in[6];
  const float* bmu = (const float*)d_in[7];
  const float* Wlv = (const float*)d_in[8];
  const float* blv = (const float*)d_in[9];
  float* out = (float*)d_out;

  // workspace layout (all 8B-aligned):
  float* buf0 = (float*)d_ws;                       // XW then T: 6.4M floats
  float* buf1 = buf0 + (size_t)N_NODES * NHID;      // agg1:      6.4M floats
  int* cnt     = (int*)(buf1 + (size_t)N_NODES * NHID);
  int* partial = cnt + 50176;
  int* off     = partial + 50176;
  int* cursor  = off + 50056;
  int* bsum    = cursor + 50176;
  int2* edata  = (int2*)(bsum + 256);               // 800000 * 8B

  dim3 blk(256);
  int gemm_grid = (N_NODES + 127) / 128;   // 391
  int edge_grid = (N_EDGES + 255) / 256;   // 3125
  int node_grid = (N_NODES + 255) / 256;   // 196
  int wave_grid = (N_NODES * 64 + 255) / 256;  // 12500

  hipMemsetAsync(cnt, 0, 50176 * sizeof(int), stream);

  // CSR build (depends only on src/dst/ew) + GEMM1 interleaved
  gemm1_kernel<<<gemm_grid, blk, 0, stream>>>(x, W1, buf0);
  hist_kernel<<<edge_grid, blk, 0, stream>>>(dst, cnt);
  scan_blocks_kernel<<<SCAN_BLOCKS, blk, 0, stream>>>(cnt, partial, bsum);
  scan_bsums_kernel<<<1, blk, 0, stream>>>(bsum);
  add_offsets_kernel<<<SCAN_BLOCKS, blk, 0, stream>>>(partial, bsum, off, cursor);
  fill_kernel<<<edge_grid, blk, 0, stream>>>(src, dst, ew, cursor, edata);

  gather1_kernel<<<wave_grid, blk, 0, stream>>>(buf0, off, edata, buf1);
  gemm2_kernel<<<gemm_grid, blk, 0, stream>>>(buf1, b1, Wmu, Wlv, buf0);
  gather2_kernel<<<wave_grid, blk, 0, stream>>>(buf0, off, edata, bmu, blv, out);
}

// Round 3
// 318.297 us; speedup vs baseline: 3.5841x; 1.3145x over previous
//
#include <hip/hip_runtime.h>
#include <hip/hip_bf16.h>

#define N_NODES 50000
#define N_EDGES 800000
#define NFEAT 256
#define NHID 128
#define LATENT 64
#define SCAN_BLOCKS 196  // ceil(50000/256)

typedef __attribute__((ext_vector_type(8))) short bf16x8;
typedef __attribute__((ext_vector_type(4))) float f32x4;
typedef __attribute__((ext_vector_type(4))) short short4v;
typedef __attribute__((ext_vector_type(4))) unsigned short ushort4v;

__device__ inline unsigned short f2bf(float f) {
  union { float f; unsigned u; } c; c.f = f;
  unsigned r = (c.u + 0x7FFFu + ((c.u >> 16) & 1u)) >> 16;
  return (unsigned short)r;
}
__device__ inline float bf2f(unsigned short u) {
  union { unsigned u; float f; } c; c.u = ((unsigned)u) << 16;
  return c.f;
}

// ---------------------------------------------------------------------------
// GEMM1: XWb[M=50000][128] = bf16( x[M][256] @ W1[256][128] )
// ---------------------------------------------------------------------------
__launch_bounds__(256)
__global__ void gemm1_kernel(const float* __restrict__ X,
                             const float* __restrict__ W1,
                             unsigned short* __restrict__ XWb) {
  __shared__ short A_lds[128][40];
  __shared__ short B_lds[128][40];
  const int t = threadIdx.x;
  const int lane = t & 63;
  const int wave = t >> 6;
  const int wm = wave >> 1, wn = wave & 1;
  const int row0 = blockIdx.x * 128;
  const int l15 = lane & 15, quad = lane >> 4;

  f32x4 acc[4][4];
#pragma unroll
  for (int i = 0; i < 4; i++)
#pragma unroll
    for (int j = 0; j < 4; j++) acc[i][j] = (f32x4){0.f, 0.f, 0.f, 0.f};

  for (int k0 = 0; k0 < NFEAT; k0 += 32) {
#pragma unroll
    for (int r = 0; r < 4; r++) {
      int i = t + 256 * r;
      int ar = i >> 3, grp = i & 7;
      int gr = row0 + ar;
      float4 v = (gr < N_NODES)
                     ? *(const float4*)(X + (size_t)gr * NFEAT + k0 + grp * 4)
                     : make_float4(0.f, 0.f, 0.f, 0.f);
      short4v s;
      s.x = f2bf(v.x); s.y = f2bf(v.y); s.z = f2bf(v.z); s.w = f2bf(v.w);
      *(short4v*)&A_lds[ar][grp * 4] = s;
    }
#pragma unroll
    for (int r = 0; r < 4; r++) {
      int i = t + 256 * r;
      int kr = i >> 5, grp = i & 31;
      float4 v = *(const float4*)(W1 + (size_t)(k0 + kr) * NHID + grp * 4);
      B_lds[grp * 4 + 0][kr] = f2bf(v.x);
      B_lds[grp * 4 + 1][kr] = f2bf(v.y);
      B_lds[grp * 4 + 2][kr] = f2bf(v.z);
      B_lds[grp * 4 + 3][kr] = f2bf(v.w);
    }
    __syncthreads();
    bf16x8 a[4], b[4];
#pragma unroll
    for (int mt = 0; mt < 4; mt++)
      a[mt] = *(const bf16x8*)&A_lds[wm * 64 + mt * 16 + l15][quad * 8];
#pragma unroll
    for (int nt = 0; nt < 4; nt++)
      b[nt] = *(const bf16x8*)&B_lds[wn * 64 + nt * 16 + l15][quad * 8];
#pragma unroll
    for (int mt = 0; mt < 4; mt++)
#pragma unroll
      for (int nt = 0; nt < 4; nt++)
        acc[mt][nt] = __builtin_amdgcn_mfma_f32_16x16x32_bf16(a[mt], b[nt], acc[mt][nt], 0, 0, 0);
    __syncthreads();
  }
#pragma unroll
  for (int mt = 0; mt < 4; mt++) {
#pragma unroll
    for (int reg = 0; reg < 4; reg++) {
      int gr = row0 + wm * 64 + mt * 16 + quad * 4 + reg;
      if (gr < N_NODES) {
#pragma unroll
        for (int nt = 0; nt < 4; nt++) {
          int gc = wn * 64 + nt * 16 + l15;
          XWb[(size_t)gr * NHID + gc] = f2bf(acc[mt][nt][reg]);
        }
      }
    }
  }
}

// ---------------------------------------------------------------------------
// GEMM2: Tb[M][128] = bf16( relu(agg1+b1) @ concat(Wmu|Wlv) )
// ---------------------------------------------------------------------------
__launch_bounds__(256)
__global__ void gemm2_kernel(const float* __restrict__ AGG,
                             const float* __restrict__ b1,
                             const float* __restrict__ Wmu,
                             const float* __restrict__ Wlv,
                             unsigned short* __restrict__ Tb) {
  __shared__ short A_lds[128][40];
  __shared__ short B_lds[128][40];
  const int t = threadIdx.x;
  const int lane = t & 63;
  const int wave = t >> 6;
  const int wm = wave >> 1, wn = wave & 1;
  const int row0 = blockIdx.x * 128;
  const int l15 = lane & 15, quad = lane >> 4;

  f32x4 acc[4][4];
#pragma unroll
  for (int i = 0; i < 4; i++)
#pragma unroll
    for (int j = 0; j < 4; j++) acc[i][j] = (f32x4){0.f, 0.f, 0.f, 0.f};

  for (int k0 = 0; k0 < NHID; k0 += 32) {
#pragma unroll
    for (int r = 0; r < 4; r++) {
      int i = t + 256 * r;
      int ar = i >> 3, grp = i & 7;
      int gr = row0 + ar;
      float4 bb = *(const float4*)(b1 + k0 + grp * 4);
      float4 v = (gr < N_NODES)
                     ? *(const float4*)(AGG + (size_t)gr * NHID + k0 + grp * 4)
                     : make_float4(0.f, 0.f, 0.f, 0.f);
      v.x = fmaxf(v.x + bb.x, 0.f);
      v.y = fmaxf(v.y + bb.y, 0.f);
      v.z = fmaxf(v.z + bb.z, 0.f);
      v.w = fmaxf(v.w + bb.w, 0.f);
      if (gr >= N_NODES) { v = make_float4(0.f, 0.f, 0.f, 0.f); }
      short4v s;
      s.x = f2bf(v.x); s.y = f2bf(v.y); s.z = f2bf(v.z); s.w = f2bf(v.w);
      *(short4v*)&A_lds[ar][grp * 4] = s;
    }
#pragma unroll
    for (int r = 0; r < 4; r++) {
      int i = t + 256 * r;
      int kr = i >> 5, grp = i & 31;
      const float* Wp = (grp < 16) ? (Wmu + (size_t)(k0 + kr) * LATENT + grp * 4)
                                   : (Wlv + (size_t)(k0 + kr) * LATENT + (grp - 16) * 4);
      float4 v = *(const float4*)Wp;
      B_lds[grp * 4 + 0][kr] = f2bf(v.x);
      B_lds[grp * 4 + 1][kr] = f2bf(v.y);
      B_lds[grp * 4 + 2][kr] = f2bf(v.z);
      B_lds[grp * 4 + 3][kr] = f2bf(v.w);
    }
    __syncthreads();
    bf16x8 a[4], b[4];
#pragma unroll
    for (int mt = 0; mt < 4; mt++)
      a[mt] = *(const bf16x8*)&A_lds[wm * 64 + mt * 16 + l15][quad * 8];
#pragma unroll
    for (int nt = 0; nt < 4; nt++)
      b[nt] = *(const bf16x8*)&B_lds[wn * 64 + nt * 16 + l15][quad * 8];
#pragma unroll
    for (int mt = 0; mt < 4; mt++)
#pragma unroll
      for (int nt = 0; nt < 4; nt++)
        acc[mt][nt] = __builtin_amdgcn_mfma_f32_16x16x32_bf16(a[mt], b[nt], acc[mt][nt], 0, 0, 0);
    __syncthreads();
  }
#pragma unroll
  for (int mt = 0; mt < 4; mt++) {
#pragma unroll
    for (int reg = 0; reg < 4; reg++) {
      int gr = row0 + wm * 64 + mt * 16 + quad * 4 + reg;
      if (gr < N_NODES) {
#pragma unroll
        for (int nt = 0; nt < 4; nt++) {
          int gc = wn * 64 + nt * 16 + l15;
          Tb[(size_t)gr * NHID + gc] = f2bf(acc[mt][nt][reg]);
        }
      }
    }
  }
}

// ---------------------------------------------------------------------------
// CSR build: histogram -> block scan -> bsum scan -> add offsets -> fill
// ---------------------------------------------------------------------------
__launch_bounds__(256)
__global__ void hist_kernel(const int* __restrict__ dst, int* __restrict__ cnt) {
  int e = blockIdx.x * 256 + threadIdx.x;
  if (e < N_EDGES) atomicAdd(&cnt[dst[e]], 1);
}

__launch_bounds__(256)
__global__ void scan_blocks_kernel(const int* __restrict__ cnt,
                                   int* __restrict__ partial,
                                   int* __restrict__ bsum) {
  __shared__ int lds[256];
  int t = threadIdx.x;
  int i = blockIdx.x * 256 + t;
  int v = (i < N_NODES) ? cnt[i] : 0;
  lds[t] = v;
  __syncthreads();
  int x = v;
  for (int ofs = 1; ofs < 256; ofs <<= 1) {
    int y = (t >= ofs) ? lds[t - ofs] : 0;
    __syncthreads();
    x += y;
    lds[t] = x;
    __syncthreads();
  }
  if (i < N_NODES) partial[i] = x - v;
  if (t == 255) bsum[blockIdx.x] = x;
}

__launch_bounds__(256)
__global__ void scan_bsums_kernel(int* __restrict__ bsum) {
  __shared__ int lds[256];
  int t = threadIdx.x;
  int v = (t < SCAN_BLOCKS) ? bsum[t] : 0;
  lds[t] = v;
  __syncthreads();
  int x = v;
  for (int ofs = 1; ofs < 256; ofs <<= 1) {
    int y = (t >= ofs) ? lds[t - ofs] : 0;
    __syncthreads();
    x += y;
    lds[t] = x;
    __syncthreads();
  }
  if (t < SCAN_BLOCKS) bsum[t] = x - v;
}

__launch_bounds__(256)
__global__ void add_offsets_kernel(const int* __restrict__ partial,
                                   const int* __restrict__ bsum,
                                   int* __restrict__ off,
                                   int* __restrict__ cursor) {
  int i = blockIdx.x * 256 + threadIdx.x;
  if (i < N_NODES) {
    int o = partial[i] + bsum[blockIdx.x];
    off[i] = o;
    cursor[i] = o;
  }
  if (i == 0) off[N_NODES] = N_EDGES;
}

__launch_bounds__(256)
__global__ void fill_kernel(const int* __restrict__ src,
                            const int* __restrict__ dst,
                            const float* __restrict__ ew,
                            int* __restrict__ cursor,
                            int2* __restrict__ edata) {
  int e = blockIdx.x * 256 + threadIdx.x;
  if (e < N_EDGES) {
    int pos = atomicAdd(&cursor[dst[e]], 1);
    edata[pos] = make_int2(src[e], __float_as_int(ew[e]));
  }
}

// ---------------------------------------------------------------------------
// Gather 1: agg[n][:] = sum_{j in CSR[n]} bf2f(XWb[src_j][:]) * w_j
// One wave per node. Half-wave per edge (32 lanes x 8B = 256B row),
// 2-deep unroll => 4 independent row loads in flight.
// ---------------------------------------------------------------------------
__launch_bounds__(256)
__global__ void gather1_kernel(const unsigned short* __restrict__ XWb,
                               const int* __restrict__ off,
                               const int2* __restrict__ edata,
                               float* __restrict__ agg) {
  int gw = (int)((blockIdx.x * blockDim.x + threadIdx.x) >> 6);
  if (gw >= N_NODES) return;
  int lane = threadIdx.x & 63;
  int half = lane >> 5;
  int col4 = lane & 31;  // covers cols 4*col4 .. 4*col4+3
  int beg = off[gw], end = off[gw + 1];
  f32x4 acc = (f32x4){0.f, 0.f, 0.f, 0.f};
  int j = beg + half;
  for (; j + 2 < end; j += 4) {
    int2 e0 = edata[j];
    int2 e1 = edata[j + 2];
    ushort4v r0 = *(const ushort4v*)(XWb + (size_t)e0.x * NHID + col4 * 4);
    ushort4v r1 = *(const ushort4v*)(XWb + (size_t)e1.x * NHID + col4 * 4);
    float w0 = __int_as_float(e0.y);
    float w1 = __int_as_float(e1.y);
    acc.x += bf2f(r0.x) * w0; acc.y += bf2f(r0.y) * w0;
    acc.z += bf2f(r0.z) * w0; acc.w += bf2f(r0.w) * w0;
    acc.x += bf2f(r1.x) * w1; acc.y += bf2f(r1.y) * w1;
    acc.z += bf2f(r1.z) * w1; acc.w += bf2f(r1.w) * w1;
  }
  if (j < end) {
    int2 e0 = edata[j];
    ushort4v r0 = *(const ushort4v*)(XWb + (size_t)e0.x * NHID + col4 * 4);
    float w0 = __int_as_float(e0.y);
    acc.x += bf2f(r0.x) * w0; acc.y += bf2f(r0.y) * w0;
    acc.z += bf2f(r0.z) * w0; acc.w += bf2f(r0.w) * w0;
  }
  // fold upper half into lower half
  acc.x += __shfl_down(acc.x, 32, 64);
  acc.y += __shfl_down(acc.y, 32, 64);
  acc.z += __shfl_down(acc.z, 32, 64);
  acc.w += __shfl_down(acc.w, 32, 64);
  if (lane < 32) {
    float4 o; o.x = acc.x; o.y = acc.y; o.z = acc.z; o.w = acc.w;
    *(float4*)(agg + (size_t)gw * NHID + col4 * 4) = o;
  }
}

// ---------------------------------------------------------------------------
// Gather 2: out_mu[n] = bmu + sum bf2f(Tb[src][0:64])*w ; out_lv likewise
// Tb row = [mu(64) | lv(64)] bf16 = 256B; same half-wave-per-edge scheme.
// ---------------------------------------------------------------------------
__launch_bounds__(256)
__global__ void gather2_kernel(const unsigned short* __restrict__ Tb,
                               const int* __restrict__ off,
                               const int2* __restrict__ edata,
                               const float* __restrict__ bmu,
                               const float* __restrict__ blv,
                               float* __restrict__ out) {
  int gw = (int)((blockIdx.x * blockDim.x + threadIdx.x) >> 6);
  if (gw >= N_NODES) return;
  int lane = threadIdx.x & 63;
  int half = lane >> 5;
  int col4 = lane & 31;
  int beg = off[gw], end = off[gw + 1];
  f32x4 acc = (f32x4){0.f, 0.f, 0.f, 0.f};
  int j = beg + half;
  for (; j + 2 < end; j += 4) {
    int2 e0 = edata[j];
    int2 e1 = edata[j + 2];
    ushort4v r0 = *(const ushort4v*)(Tb + (size_t)e0.x * NHID + col4 * 4);
    ushort4v r1 = *(const ushort4v*)(Tb + (size_t)e1.x * NHID + col4 * 4);
    float w0 = __int_as_float(e0.y);
    float w1 = __int_as_float(e1.y);
    acc.x += bf2f(r0.x) * w0; acc.y += bf2f(r0.y) * w0;
    acc.z += bf2f(r0.z) * w0; acc.w += bf2f(r0.w) * w0;
    acc.x += bf2f(r1.x) * w1; acc.y += bf2f(r1.y) * w1;
    acc.z += bf2f(r1.z) * w1; acc.w += bf2f(r1.w) * w1;
  }
  if (j < end) {
    int2 e0 = edata[j];
    ushort4v r0 = *(const ushort4v*)(Tb + (size_t)e0.x * NHID + col4 * 4);
    float w0 = __int_as_float(e0.y);
    acc.x += bf2f(r0.x) * w0; acc.y += bf2f(r0.y) * w0;
    acc.z += bf2f(r0.z) * w0; acc.w += bf2f(r0.w) * w0;
  }
  acc.x += __shfl_down(acc.x, 32, 64);
  acc.y += __shfl_down(acc.y, 32, 64);
  acc.z += __shfl_down(acc.z, 32, 64);
  acc.w += __shfl_down(acc.w, 32, 64);
  if (lane < 16) {
    // mu: cols 4*col4 .. 4*col4+3 (col4 in [0,16))
    float4 bb = *(const float4*)(bmu + col4 * 4);
    float4 o; o.x = acc.x + bb.x; o.y = acc.y + bb.y;
    o.z = acc.z + bb.z; o.w = acc.w + bb.w;
    *(float4*)(out + (size_t)gw * LATENT + col4 * 4) = o;
  } else if (lane < 32) {
    int c = col4 - 16;  // lv cols 4c..4c+3
    float4 bb = *(const float4*)(blv + c * 4);
    float4 o; o.x = acc.x + bb.x; o.y = acc.y + bb.y;
    o.z = acc.z + bb.z; o.w = acc.w + bb.w;
    *(float4*)(out + (size_t)N_NODES * LATENT + (size_t)gw * LATENT + c * 4) = o;
  }
}

extern "C" void kernel_launch(void* const* d_in, const int* in_sizes, int n_in,
                              void* d_out, int out_size, void* d_ws, size_t ws_size,
                              hipStream_t stream) {
  const float* x   = (const float*)d_in[0];
  const int*   src = (const int*)d_in[1];
  const int*   dst = (const int*)d_in[2];
  const float* ew  = (const float*)d_in[3];
  const float* W1  = (const float*)d_in[4];
  const float* b1  = (const float*)d_in[5];
  const float* Wmu = (const float*)d_in[6];
  const float* bmu = (const float*)d_in[7];
  const float* Wlv = (const float*)d_in[8];
  const float* blv = (const float*)d_in[9];
  float* out = (float*)d_out;

  // workspace layout (16B aligned segments):
  unsigned short* bufb = (unsigned short*)d_ws;          // XWb then Tb: 6.4M bf16 (12.8MB)
  float* agg1 = (float*)(bufb + (size_t)N_NODES * NHID); // 6.4M floats (25.6MB)
  int* cnt     = (int*)(agg1 + (size_t)N_NODES * NHID);
  int* partial = cnt + 50176;
  int* off     = partial + 50176;
  int* cursor  = off + 50056;
  int* bsum    = cursor + 50176;
  int2* edata  = (int2*)(bsum + 256);                    // 800000 * 8B

  dim3 blk(256);
  int gemm_grid = (N_NODES + 127) / 128;       // 391
  int edge_grid = (N_EDGES + 255) / 256;       // 3125
  int wave_grid = (N_NODES * 64 + 255) / 256;  // 12500

  hipMemsetAsync(cnt, 0, 50176 * sizeof(int), stream);

  gemm1_kernel<<<gemm_grid, blk, 0, stream>>>(x, W1, bufb);
  hist_kernel<<<edge_grid, blk, 0, stream>>>(dst, cnt);
  scan_blocks_kernel<<<SCAN_BLOCKS, blk, 0, stream>>>(cnt, partial, bsum);
  scan_bsums_kernel<<<1, blk, 0, stream>>>(bsum);
  add_offsets_kernel<<<SCAN_BLOCKS, blk, 0, stream>>>(partial, bsum, off, cursor);
  fill_kernel<<<edge_grid, blk, 0, stream>>>(src, dst, ew, cursor, edata);

  gather1_kernel<<<wave_grid, blk, 0, stream>>>(bufb, off, edata, agg1);
  gemm2_kernel<<<gemm_grid, blk, 0, stream>>>(agg1, b1, Wmu, Wlv, bufb);
  gather2_kernel<<<wave_grid, blk, 0, stream>>>(bufb, off, edata, bmu, blv, out);
}

// Round 4
// 284.305 us; speedup vs baseline: 4.0126x; 1.1196x over previous
//
#include <hip/hip_runtime.h>
#include <hip/hip_bf16.h>

#define N_NODES 50000
#define N_EDGES 800000
#define NFEAT 256
#define NHID 128
#define LATENT 64
#define NB 98      // coarse buckets: dst >> 9 (512 nodes each; 98*512 = 50176)
#define BSH 9
#define CT 4096    // edges per coarse tile
#define CBLK 196   // ceil(800000/4096)

typedef __attribute__((ext_vector_type(8))) short bf16x8;
typedef __attribute__((ext_vector_type(4))) float f32x4;
typedef __attribute__((ext_vector_type(4))) short short4v;
typedef __attribute__((ext_vector_type(4))) unsigned short ushort4v;

__device__ inline unsigned short f2bf(float f) {
  union { float f; unsigned u; } c; c.f = f;
  unsigned r = (c.u + 0x7FFFu + ((c.u >> 16) & 1u)) >> 16;
  return (unsigned short)r;
}
__device__ inline float bf2f(unsigned short u) {
  union { unsigned u; float f; } c; c.u = ((unsigned)u) << 16;
  return c.f;
}

// ---------------------------------------------------------------------------
// GEMM1: XWb[M=50000][128] = bf16( x[M][256] @ W1[256][128] )
// ---------------------------------------------------------------------------
__launch_bounds__(256)
__global__ void gemm1_kernel(const float* __restrict__ X,
                             const float* __restrict__ W1,
                             unsigned short* __restrict__ XWb) {
  __shared__ short A_lds[128][40];
  __shared__ short B_lds[128][40];
  const int t = threadIdx.x;
  const int lane = t & 63;
  const int wave = t >> 6;
  const int wm = wave >> 1, wn = wave & 1;
  const int row0 = blockIdx.x * 128;
  const int l15 = lane & 15, quad = lane >> 4;

  f32x4 acc[4][4];
#pragma unroll
  for (int i = 0; i < 4; i++)
#pragma unroll
    for (int j = 0; j < 4; j++) acc[i][j] = (f32x4){0.f, 0.f, 0.f, 0.f};

  for (int k0 = 0; k0 < NFEAT; k0 += 32) {
#pragma unroll
    for (int r = 0; r < 4; r++) {
      int i = t + 256 * r;
      int ar = i >> 3, grp = i & 7;
      int gr = row0 + ar;
      float4 v = (gr < N_NODES)
                     ? *(const float4*)(X + (size_t)gr * NFEAT + k0 + grp * 4)
                     : make_float4(0.f, 0.f, 0.f, 0.f);
      short4v s;
      s.x = f2bf(v.x); s.y = f2bf(v.y); s.z = f2bf(v.z); s.w = f2bf(v.w);
      *(short4v*)&A_lds[ar][grp * 4] = s;
    }
#pragma unroll
    for (int r = 0; r < 4; r++) {
      int i = t + 256 * r;
      int kr = i >> 5, grp = i & 31;
      float4 v = *(const float4*)(W1 + (size_t)(k0 + kr) * NHID + grp * 4);
      B_lds[grp * 4 + 0][kr] = f2bf(v.x);
      B_lds[grp * 4 + 1][kr] = f2bf(v.y);
      B_lds[grp * 4 + 2][kr] = f2bf(v.z);
      B_lds[grp * 4 + 3][kr] = f2bf(v.w);
    }
    __syncthreads();
    bf16x8 a[4], b[4];
#pragma unroll
    for (int mt = 0; mt < 4; mt++)
      a[mt] = *(const bf16x8*)&A_lds[wm * 64 + mt * 16 + l15][quad * 8];
#pragma unroll
    for (int nt = 0; nt < 4; nt++)
      b[nt] = *(const bf16x8*)&B_lds[wn * 64 + nt * 16 + l15][quad * 8];
#pragma unroll
    for (int mt = 0; mt < 4; mt++)
#pragma unroll
      for (int nt = 0; nt < 4; nt++)
        acc[mt][nt] = __builtin_amdgcn_mfma_f32_16x16x32_bf16(a[mt], b[nt], acc[mt][nt], 0, 0, 0);
    __syncthreads();
  }
#pragma unroll
  for (int mt = 0; mt < 4; mt++) {
#pragma unroll
    for (int reg = 0; reg < 4; reg++) {
      int gr = row0 + wm * 64 + mt * 16 + quad * 4 + reg;
      if (gr < N_NODES) {
#pragma unroll
        for (int nt = 0; nt < 4; nt++) {
          int gc = wn * 64 + nt * 16 + l15;
          XWb[(size_t)gr * NHID + gc] = f2bf(acc[mt][nt][reg]);
        }
      }
    }
  }
}

// ---------------------------------------------------------------------------
// GEMM2: Tb[M][128] = bf16( relu(agg1+b1) @ concat(Wmu|Wlv) )
// ---------------------------------------------------------------------------
__launch_bounds__(256)
__global__ void gemm2_kernel(const float* __restrict__ AGG,
                             const float* __restrict__ b1,
                             const float* __restrict__ Wmu,
                             const float* __restrict__ Wlv,
                             unsigned short* __restrict__ Tb) {
  __shared__ short A_lds[128][40];
  __shared__ short B_lds[128][40];
  const int t = threadIdx.x;
  const int lane = t & 63;
  const int wave = t >> 6;
  const int wm = wave >> 1, wn = wave & 1;
  const int row0 = blockIdx.x * 128;
  const int l15 = lane & 15, quad = lane >> 4;

  f32x4 acc[4][4];
#pragma unroll
  for (int i = 0; i < 4; i++)
#pragma unroll
    for (int j = 0; j < 4; j++) acc[i][j] = (f32x4){0.f, 0.f, 0.f, 0.f};

  for (int k0 = 0; k0 < NHID; k0 += 32) {
#pragma unroll
    for (int r = 0; r < 4; r++) {
      int i = t + 256 * r;
      int ar = i >> 3, grp = i & 7;
      int gr = row0 + ar;
      float4 bb = *(const float4*)(b1 + k0 + grp * 4);
      float4 v = (gr < N_NODES)
                     ? *(const float4*)(AGG + (size_t)gr * NHID + k0 + grp * 4)
                     : make_float4(0.f, 0.f, 0.f, 0.f);
      v.x = fmaxf(v.x + bb.x, 0.f);
      v.y = fmaxf(v.y + bb.y, 0.f);
      v.z = fmaxf(v.z + bb.z, 0.f);
      v.w = fmaxf(v.w + bb.w, 0.f);
      if (gr >= N_NODES) { v = make_float4(0.f, 0.f, 0.f, 0.f); }
      short4v s;
      s.x = f2bf(v.x); s.y = f2bf(v.y); s.z = f2bf(v.z); s.w = f2bf(v.w);
      *(short4v*)&A_lds[ar][grp * 4] = s;
    }
#pragma unroll
    for (int r = 0; r < 4; r++) {
      int i = t + 256 * r;
      int kr = i >> 5, grp = i & 31;
      const float* Wp = (grp < 16) ? (Wmu + (size_t)(k0 + kr) * LATENT + grp * 4)
                                   : (Wlv + (size_t)(k0 + kr) * LATENT + (grp - 16) * 4);
      float4 v = *(const float4*)Wp;
      B_lds[grp * 4 + 0][kr] = f2bf(v.x);
      B_lds[grp * 4 + 1][kr] = f2bf(v.y);
      B_lds[grp * 4 + 2][kr] = f2bf(v.z);
      B_lds[grp * 4 + 3][kr] = f2bf(v.w);
    }
    __syncthreads();
    bf16x8 a[4], b[4];
#pragma unroll
    for (int mt = 0; mt < 4; mt++)
      a[mt] = *(const bf16x8*)&A_lds[wm * 64 + mt * 16 + l15][quad * 8];
#pragma unroll
    for (int nt = 0; nt < 4; nt++)
      b[nt] = *(const bf16x8*)&B_lds[wn * 64 + nt * 16 + l15][quad * 8];
#pragma unroll
    for (int mt = 0; mt < 4; mt++)
#pragma unroll
      for (int nt = 0; nt < 4; nt++)
        acc[mt][nt] = __builtin_amdgcn_mfma_f32_16x16x32_bf16(a[mt], b[nt], acc[mt][nt], 0, 0, 0);
    __syncthreads();
  }
#pragma unroll
  for (int mt = 0; mt < 4; mt++) {
#pragma unroll
    for (int reg = 0; reg < 4; reg++) {
      int gr = row0 + wm * 64 + mt * 16 + quad * 4 + reg;
      if (gr < N_NODES) {
#pragma unroll
        for (int nt = 0; nt < 4; nt++) {
          int gc = wn * 64 + nt * 16 + l15;
          Tb[(size_t)gr * NHID + gc] = f2bf(acc[mt][nt][reg]);
        }
      }
    }
  }
}

// ---------------------------------------------------------------------------
// CSR build, phase 0: coarse histogram over NB buckets (LDS-staged)
// ---------------------------------------------------------------------------
__launch_bounds__(256)
__global__ void coarse_hist_kernel(const int* __restrict__ dst,
                                   int* __restrict__ chist) {
  __shared__ int h[NB];
  int t = threadIdx.x;
  if (t < NB) h[t] = 0;
  __syncthreads();
  int base = blockIdx.x * CT;
#pragma unroll
  for (int k = 0; k < 16; k++) {
    int e = base + t + k * 256;
    if (e < N_EDGES) atomicAdd(&h[dst[e] >> BSH], 1);
  }
  __syncthreads();
  if (t < NB && h[t]) atomicAdd(&chist[t], h[t]);
}

// ---------------------------------------------------------------------------
// phase 0b: exclusive scan of NB bucket counts; init bucket cursors
// ---------------------------------------------------------------------------
__launch_bounds__(128)
__global__ void coarse_scan_kernel(const int* __restrict__ chist,
                                   int* __restrict__ coff,
                                   int* __restrict__ bcur) {
  __shared__ int lds[128];
  int t = threadIdx.x;
  int v = (t < NB) ? chist[t] : 0;
  lds[t] = v;
  __syncthreads();
  int x = v;
  for (int ofs = 1; ofs < 128; ofs <<= 1) {
    int y = (t >= ofs) ? lds[t - ofs] : 0;
    __syncthreads();
    x += y;
    lds[t] = x;
    __syncthreads();
  }
  if (t < NB) {
    int o = x - v;
    coff[t] = o;
    bcur[t] = o;
  }
  if (t == NB) coff[NB] = N_EDGES;
}

// ---------------------------------------------------------------------------
// phase 1: partition edges into NB coarse buckets.
// Per block: LDS-stage CT edges sorted by bucket, reserve space with NB
// batched atomics, write contiguous runs. Edge packed: x=(src<<16)|dst, y=w.
// ---------------------------------------------------------------------------
__launch_bounds__(256)
__global__ void coarse_part_kernel(const int* __restrict__ src,
                                   const int* __restrict__ dst,
                                   const float* __restrict__ ew,
                                   int* __restrict__ bcur,
                                   int2* __restrict__ part) {
  __shared__ int hist[NB], start[NB], cur[NB], gbase[NB];
  __shared__ int sc[128];
  __shared__ int2 stage[CT];
  int t = threadIdx.x;
  if (t < NB) hist[t] = 0;
  __syncthreads();
  int base = blockIdx.x * CT;
  // pass A: LDS histogram
#pragma unroll
  for (int k = 0; k < 16; k++) {
    int e = base + t + k * 256;
    if (e < N_EDGES) atomicAdd(&hist[dst[e] >> BSH], 1);
  }
  __syncthreads();
  // exclusive scan of hist (Hillis-Steele over 128, all threads at barriers)
  int v = (t < NB) ? hist[t] : 0;
  if (t < 128) sc[t] = v;
  __syncthreads();
  int x = v;
  for (int ofs = 1; ofs < 128; ofs <<= 1) {
    int y = (t >= ofs && t < 128) ? sc[t - ofs] : 0;
    __syncthreads();
    if (t < 128) { x += y; sc[t] = x; }
    __syncthreads();
  }
  if (t < NB) {
    int st = x - v;
    start[t] = st;
    cur[t] = st;
    gbase[t] = atomicAdd(&bcur[t], hist[t]);
  }
  __syncthreads();
  // pass B: stage bucket-sorted into LDS
#pragma unroll
  for (int k = 0; k < 16; k++) {
    int e = base + t + k * 256;
    if (e < N_EDGES) {
      int d = dst[e];
      int b = d >> BSH;
      int lp = atomicAdd(&cur[b], 1);
      stage[lp] = make_int2((src[e] << 16) | d, __float_as_int(ew[e]));
    }
  }
  __syncthreads();
  // pass C: coalesced run writes
  int nedge = min(CT, N_EDGES - base);
  for (int i = t; i < nedge; i += 256) {
    int2 e = stage[i];
    int b = (e.x & 0xffff) >> BSH;
    part[gbase[b] + (i - start[b])] = e;
  }
}

// ---------------------------------------------------------------------------
// phase 2: per-bucket fine sort. One block per bucket: node histogram + scan
// in LDS (512 nodes), emits off[] and dst-sorted edata. All global R/W within
// one ~66KB window -> single-XCD L2 locality, no write amplification.
// ---------------------------------------------------------------------------
__launch_bounds__(256)
__global__ void fine_kernel(const int* __restrict__ coff,
                            const int2* __restrict__ part,
                            int* __restrict__ off,
                            int2* __restrict__ edata) {
  __shared__ int nh[512];
  __shared__ int sc[256];
  int t = threadIdx.x;
  int b = blockIdx.x;
  int beg = coff[b], end = coff[b + 1];
  int nb = b << BSH;
  nh[t] = 0;
  nh[t + 256] = 0;
  __syncthreads();
  for (int i = beg + t; i < end; i += 256) {
    int d = part[i].x & 0xffff;
    atomicAdd(&nh[d - nb], 1);
  }
  __syncthreads();
  // exclusive scan over 512 (pairs + Hillis-Steele over 256 partials)
  int a0 = nh[2 * t], a1 = nh[2 * t + 1];
  int s = a0 + a1;
  sc[t] = s;
  __syncthreads();
  int x = s;
  for (int ofs = 1; ofs < 256; ofs <<= 1) {
    int y = (t >= ofs) ? sc[t - ofs] : 0;
    __syncthreads();
    x += y;
    sc[t] = x;
    __syncthreads();
  }
  int pairExcl = x - s;
  int e0 = beg + pairExcl;
  int e1 = beg + pairExcl + a0;
  __syncthreads();  // done reading nh as counts
  nh[2 * t] = e0;
  nh[2 * t + 1] = e1;
  int g0 = nb + 2 * t, g1 = nb + 2 * t + 1;
  if (g0 <= N_NODES) off[g0] = e0;
  if (g1 <= N_NODES) off[g1] = e1;
  __syncthreads();
  // scatter into final CSR order (writes stay within this bucket's window)
  for (int i = beg + t; i < end; i += 256) {
    int2 e = part[i];
    int d = e.x & 0xffff;
    int pos = atomicAdd(&nh[d - nb], 1);
    edata[pos] = make_int2((int)(((unsigned)e.x) >> 16), e.y);
  }
}

// ---------------------------------------------------------------------------
// Gather 1: agg[n][:] = sum_{j in CSR[n]} bf2f(XWb[src_j][:]) * w_j
// One wave per node; half-wave per edge (32 lanes x 8B = 256B row), x2 unroll.
// ---------------------------------------------------------------------------
__launch_bounds__(256)
__global__ void gather1_kernel(const unsigned short* __restrict__ XWb,
                               const int* __restrict__ off,
                               const int2* __restrict__ edata,
                               float* __restrict__ agg) {
  int gw = (int)((blockIdx.x * blockDim.x + threadIdx.x) >> 6);
  if (gw >= N_NODES) return;
  int lane = threadIdx.x & 63;
  int half = lane >> 5;
  int col4 = lane & 31;
  int beg = off[gw], end = off[gw + 1];
  f32x4 acc = (f32x4){0.f, 0.f, 0.f, 0.f};
  int j = beg + half;
  for (; j + 2 < end; j += 4) {
    int2 e0 = edata[j];
    int2 e1 = edata[j + 2];
    ushort4v r0 = *(const ushort4v*)(XWb + (size_t)e0.x * NHID + col4 * 4);
    ushort4v r1 = *(const ushort4v*)(XWb + (size_t)e1.x * NHID + col4 * 4);
    float w0 = __int_as_float(e0.y);
    float w1 = __int_as_float(e1.y);
    acc.x += bf2f(r0.x) * w0; acc.y += bf2f(r0.y) * w0;
    acc.z += bf2f(r0.z) * w0; acc.w += bf2f(r0.w) * w0;
    acc.x += bf2f(r1.x) * w1; acc.y += bf2f(r1.y) * w1;
    acc.z += bf2f(r1.z) * w1; acc.w += bf2f(r1.w) * w1;
  }
  if (j < end) {
    int2 e0 = edata[j];
    ushort4v r0 = *(const ushort4v*)(XWb + (size_t)e0.x * NHID + col4 * 4);
    float w0 = __int_as_float(e0.y);
    acc.x += bf2f(r0.x) * w0; acc.y += bf2f(r0.y) * w0;
    acc.z += bf2f(r0.z) * w0; acc.w += bf2f(r0.w) * w0;
  }
  acc.x += __shfl_down(acc.x, 32, 64);
  acc.y += __shfl_down(acc.y, 32, 64);
  acc.z += __shfl_down(acc.z, 32, 64);
  acc.w += __shfl_down(acc.w, 32, 64);
  if (lane < 32) {
    float4 o; o.x = acc.x; o.y = acc.y; o.z = acc.z; o.w = acc.w;
    *(float4*)(agg + (size_t)gw * NHID + col4 * 4) = o;
  }
}

// ---------------------------------------------------------------------------
// Gather 2: out_mu[n] = bmu + sum bf2f(Tb[src][0:64])*w ; out_lv likewise
// ---------------------------------------------------------------------------
__launch_bounds__(256)
__global__ void gather2_kernel(const unsigned short* __restrict__ Tb,
                               const int* __restrict__ off,
                               const int2* __restrict__ edata,
                               const float* __restrict__ bmu,
                               const float* __restrict__ blv,
                               float* __restrict__ out) {
  int gw = (int)((blockIdx.x * blockDim.x + threadIdx.x) >> 6);
  if (gw >= N_NODES) return;
  int lane = threadIdx.x & 63;
  int half = lane >> 5;
  int col4 = lane & 31;
  int beg = off[gw], end = off[gw + 1];
  f32x4 acc = (f32x4){0.f, 0.f, 0.f, 0.f};
  int j = beg + half;
  for (; j + 2 < end; j += 4) {
    int2 e0 = edata[j];
    int2 e1 = edata[j + 2];
    ushort4v r0 = *(const ushort4v*)(Tb + (size_t)e0.x * NHID + col4 * 4);
    ushort4v r1 = *(const ushort4v*)(Tb + (size_t)e1.x * NHID + col4 * 4);
    float w0 = __int_as_float(e0.y);
    float w1 = __int_as_float(e1.y);
    acc.x += bf2f(r0.x) * w0; acc.y += bf2f(r0.y) * w0;
    acc.z += bf2f(r0.z) * w0; acc.w += bf2f(r0.w) * w0;
    acc.x += bf2f(r1.x) * w1; acc.y += bf2f(r1.y) * w1;
    acc.z += bf2f(r1.z) * w1; acc.w += bf2f(r1.w) * w1;
  }
  if (j < end) {
    int2 e0 = edata[j];
    ushort4v r0 = *(const ushort4v*)(Tb + (size_t)e0.x * NHID + col4 * 4);
    float w0 = __int_as_float(e0.y);
    acc.x += bf2f(r0.x) * w0; acc.y += bf2f(r0.y) * w0;
    acc.z += bf2f(r0.z) * w0; acc.w += bf2f(r0.w) * w0;
  }
  acc.x += __shfl_down(acc.x, 32, 64);
  acc.y += __shfl_down(acc.y, 32, 64);
  acc.z += __shfl_down(acc.z, 32, 64);
  acc.w += __shfl_down(acc.w, 32, 64);
  if (lane < 16) {
    float4 bb = *(const float4*)(bmu + col4 * 4);
    float4 o; o.x = acc.x + bb.x; o.y = acc.y + bb.y;
    o.z = acc.z + bb.z; o.w = acc.w + bb.w;
    *(float4*)(out + (size_t)gw * LATENT + col4 * 4) = o;
  } else if (lane < 32) {
    int c = col4 - 16;
    float4 bb = *(const float4*)(blv + c * 4);
    float4 o; o.x = acc.x + bb.x; o.y = acc.y + bb.y;
    o.z = acc.z + bb.z; o.w = acc.w + bb.w;
    *(float4*)(out + (size_t)N_NODES * LATENT + (size_t)gw * LATENT + c * 4) = o;
  }
}

extern "C" void kernel_launch(void* const* d_in, const int* in_sizes, int n_in,
                              void* d_out, int out_size, void* d_ws, size_t ws_size,
                              hipStream_t stream) {
  const float* x   = (const float*)d_in[0];
  const int*   src = (const int*)d_in[1];
  const int*   dst = (const int*)d_in[2];
  const float* ew  = (const float*)d_in[3];
  const float* W1  = (const float*)d_in[4];
  const float* b1  = (const float*)d_in[5];
  const float* Wmu = (const float*)d_in[6];
  const float* bmu = (const float*)d_in[7];
  const float* Wlv = (const float*)d_in[8];
  const float* blv = (const float*)d_in[9];
  float* out = (float*)d_out;

  // workspace layout (8/16B aligned segments):
  unsigned short* bufb = (unsigned short*)d_ws;            // XWb then Tb (12.8MB)
  float* agg1 = (float*)(bufb + (size_t)N_NODES * NHID);   // 25.6MB
  int2* part  = (int2*)(agg1 + (size_t)N_NODES * NHID);    // 6.4MB
  int2* edata = part + N_EDGES;                            // 6.4MB
  int* off    = (int*)(edata + N_EDGES);                   // 50001 -> pad 50048
  int* chist  = off + 50048;                               // 98 -> pad 128
  int* coff   = chist + 128;                               // 99 -> pad 128
  int* bcur   = coff + 128;                                // 98 -> pad 128

  dim3 blk(256);
  int gemm_grid = (N_NODES + 127) / 128;       // 391
  int wave_grid = (N_NODES * 64 + 255) / 256;  // 12500

  hipMemsetAsync(chist, 0, 128 * sizeof(int), stream);

  gemm1_kernel<<<gemm_grid, blk, 0, stream>>>(x, W1, bufb);
  coarse_hist_kernel<<<CBLK, blk, 0, stream>>>(dst, chist);
  coarse_scan_kernel<<<1, 128, 0, stream>>>(chist, coff, bcur);
  coarse_part_kernel<<<CBLK, blk, 0, stream>>>(src, dst, ew, bcur, part);
  fine_kernel<<<NB, blk, 0, stream>>>(coff, part, off, edata);

  gather1_kernel<<<wave_grid, blk, 0, stream>>>(bufb, off, edata, agg1);
  gemm2_kernel<<<gemm_grid, blk, 0, stream>>>(agg1, b1, Wmu, Wlv, bufb);
  gather2_kernel<<<wave_grid, blk, 0, stream>>>(bufb, off, edata, bmu, blv, out);
}

// Round 5
// 261.332 us; speedup vs baseline: 4.3653x; 1.0879x over previous
//
#include <hip/hip_runtime.h>
#include <hip/hip_bf16.h>

#define N_NODES 50000
#define N_EDGES 800000
#define NFEAT 256
#define NHID 128
#define LATENT 64
#define NB 98      // coarse buckets: dst >> 9 (512 nodes each; 98*512 = 50176)
#define BSH 9
#define CT 4096    // edges per coarse tile
#define CBLK 196   // ceil(800000/4096)

typedef __attribute__((ext_vector_type(8))) short bf16x8;
typedef __attribute__((ext_vector_type(4))) float f32x4;
typedef __attribute__((ext_vector_type(4))) short short4v;
typedef __attribute__((ext_vector_type(8))) short short8v;
typedef __attribute__((ext_vector_type(4))) unsigned short ushort4v;

__device__ inline unsigned short f2bf(float f) {
  union { float f; unsigned u; } c; c.f = f;
  unsigned r = (c.u + 0x7FFFu + ((c.u >> 16) & 1u)) >> 16;
  return (unsigned short)r;
}
__device__ inline float bf2f(unsigned short u) {
  union { unsigned u; float f; } c; c.u = ((unsigned)u) << 16;
  return c.f;
}

// ---------------------------------------------------------------------------
// Prep: W1T[n][k] = bf16(W1[k][n])  (128 x 256)
//       WcT[n][k] = bf16(concat(Wmu|Wlv)[k][n])  (128 x 128)
// blocks 0..127: W1T row b; blocks 128..255: WcT row b-128.
// ---------------------------------------------------------------------------
__launch_bounds__(256)
__global__ void prep_w_kernel(const float* __restrict__ W1,
                              const float* __restrict__ Wmu,
                              const float* __restrict__ Wlv,
                              unsigned short* __restrict__ W1T,
                              unsigned short* __restrict__ WcT) {
  int b = blockIdx.x;
  int t = threadIdx.x;
  if (b < 128) {
    // W1T[b][t] = W1[t][b], t in [0,256)
    W1T[b * NFEAT + t] = f2bf(W1[(size_t)t * NHID + b]);
  } else {
    int n = b - 128;
    if (t < NHID) {
      float v = (n < 64) ? Wmu[(size_t)t * LATENT + n]
                         : Wlv[(size_t)t * LATENT + (n - 64)];
      WcT[n * NHID + t] = f2bf(v);
    }
  }
}

// ---------------------------------------------------------------------------
// GEMM1: XWb[M=50000][128] = bf16( x[M][256] @ W1[256][128] )
// 64-row tile per block (grid 782). 4 waves; wave w owns cols [w*32, w*32+32).
// A staged in LDS (64x32 bf16); B fragments loaded directly from W1T (L2).
// ---------------------------------------------------------------------------
__launch_bounds__(256)
__global__ void gemm1_kernel(const float* __restrict__ X,
                             const unsigned short* __restrict__ W1T,
                             unsigned short* __restrict__ XWb) {
  __shared__ short A_lds[64][40];
  const int t = threadIdx.x;
  const int lane = t & 63;
  const int wave = t >> 6;
  const int row0 = blockIdx.x * 64;
  const int l15 = lane & 15, quad = lane >> 4;
  const int srow = t >> 2, skg = t & 3;  // staging: row, k-group(8 floats)

  f32x4 acc[4][2];
#pragma unroll
  for (int i = 0; i < 4; i++)
#pragma unroll
    for (int j = 0; j < 2; j++) acc[i][j] = (f32x4){0.f, 0.f, 0.f, 0.f};

  for (int k0 = 0; k0 < NFEAT; k0 += 32) {
    // stage A: 64 rows x 32 k. thread -> (row, 8 consecutive k)
    int gr = row0 + srow;
    float4 v0, v1;
    if (gr < N_NODES) {
      const float* p = X + (size_t)gr * NFEAT + k0 + skg * 8;
      v0 = *(const float4*)p;
      v1 = *(const float4*)(p + 4);
    } else {
      v0 = make_float4(0.f, 0.f, 0.f, 0.f);
      v1 = v0;
    }
    short8v s;
    s[0] = f2bf(v0.x); s[1] = f2bf(v0.y); s[2] = f2bf(v0.z); s[3] = f2bf(v0.w);
    s[4] = f2bf(v1.x); s[5] = f2bf(v1.y); s[6] = f2bf(v1.z); s[7] = f2bf(v1.w);
    __syncthreads();  // protect prior iteration's reads
    *(short8v*)&A_lds[srow][skg * 8] = s;
    __syncthreads();

    bf16x8 a[4], b[2];
#pragma unroll
    for (int mt = 0; mt < 4; mt++)
      a[mt] = *(const bf16x8*)&A_lds[mt * 16 + l15][quad * 8];
#pragma unroll
    for (int nt = 0; nt < 2; nt++) {
      int n = wave * 32 + nt * 16 + l15;
      b[nt] = *(const bf16x8*)(W1T + (size_t)n * NFEAT + k0 + quad * 8);
    }
#pragma unroll
    for (int mt = 0; mt < 4; mt++)
#pragma unroll
      for (int nt = 0; nt < 2; nt++)
        acc[mt][nt] = __builtin_amdgcn_mfma_f32_16x16x32_bf16(a[mt], b[nt], acc[mt][nt], 0, 0, 0);
  }
#pragma unroll
  for (int mt = 0; mt < 4; mt++) {
#pragma unroll
    for (int reg = 0; reg < 4; reg++) {
      int gr = row0 + mt * 16 + quad * 4 + reg;
      if (gr < N_NODES) {
#pragma unroll
        for (int nt = 0; nt < 2; nt++) {
          int gc = wave * 32 + nt * 16 + l15;
          XWb[(size_t)gr * NHID + gc] = f2bf(acc[mt][nt][reg]);
        }
      }
    }
  }
}

// ---------------------------------------------------------------------------
// GEMM2: Tb[M][128] = bf16( relu(agg1+b1) @ concat(Wmu|Wlv) )
// same structure; K=128 (4 k-steps); bias+relu fused into A staging.
// ---------------------------------------------------------------------------
__launch_bounds__(256)
__global__ void gemm2_kernel(const float* __restrict__ AGG,
                             const float* __restrict__ b1,
                             const unsigned short* __restrict__ WcT,
                             unsigned short* __restrict__ Tb) {
  __shared__ short A_lds[64][40];
  const int t = threadIdx.x;
  const int lane = t & 63;
  const int wave = t >> 6;
  const int row0 = blockIdx.x * 64;
  const int l15 = lane & 15, quad = lane >> 4;
  const int srow = t >> 2, skg = t & 3;

  f32x4 acc[4][2];
#pragma unroll
  for (int i = 0; i < 4; i++)
#pragma unroll
    for (int j = 0; j < 2; j++) acc[i][j] = (f32x4){0.f, 0.f, 0.f, 0.f};

  for (int k0 = 0; k0 < NHID; k0 += 32) {
    int gr = row0 + srow;
    float4 v0, v1;
    const float* bp = b1 + k0 + skg * 8;
    float4 bb0 = *(const float4*)bp;
    float4 bb1 = *(const float4*)(bp + 4);
    if (gr < N_NODES) {
      const float* p = AGG + (size_t)gr * NHID + k0 + skg * 8;
      v0 = *(const float4*)p;
      v1 = *(const float4*)(p + 4);
      v0.x = fmaxf(v0.x + bb0.x, 0.f); v0.y = fmaxf(v0.y + bb0.y, 0.f);
      v0.z = fmaxf(v0.z + bb0.z, 0.f); v0.w = fmaxf(v0.w + bb0.w, 0.f);
      v1.x = fmaxf(v1.x + bb1.x, 0.f); v1.y = fmaxf(v1.y + bb1.y, 0.f);
      v1.z = fmaxf(v1.z + bb1.z, 0.f); v1.w = fmaxf(v1.w + bb1.w, 0.f);
    } else {
      v0 = make_float4(0.f, 0.f, 0.f, 0.f);
      v1 = v0;
    }
    short8v s;
    s[0] = f2bf(v0.x); s[1] = f2bf(v0.y); s[2] = f2bf(v0.z); s[3] = f2bf(v0.w);
    s[4] = f2bf(v1.x); s[5] = f2bf(v1.y); s[6] = f2bf(v1.z); s[7] = f2bf(v1.w);
    __syncthreads();
    *(short8v*)&A_lds[srow][skg * 8] = s;
    __syncthreads();

    bf16x8 a[4], b[2];
#pragma unroll
    for (int mt = 0; mt < 4; mt++)
      a[mt] = *(const bf16x8*)&A_lds[mt * 16 + l15][quad * 8];
#pragma unroll
    for (int nt = 0; nt < 2; nt++) {
      int n = wave * 32 + nt * 16 + l15;
      b[nt] = *(const bf16x8*)(WcT + (size_t)n * NHID + k0 + quad * 8);
    }
#pragma unroll
    for (int mt = 0; mt < 4; mt++)
#pragma unroll
      for (int nt = 0; nt < 2; nt++)
        acc[mt][nt] = __builtin_amdgcn_mfma_f32_16x16x32_bf16(a[mt], b[nt], acc[mt][nt], 0, 0, 0);
  }
#pragma unroll
  for (int mt = 0; mt < 4; mt++) {
#pragma unroll
    for (int reg = 0; reg < 4; reg++) {
      int gr = row0 + mt * 16 + quad * 4 + reg;
      if (gr < N_NODES) {
#pragma unroll
        for (int nt = 0; nt < 2; nt++) {
          int gc = wave * 32 + nt * 16 + l15;
          Tb[(size_t)gr * NHID + gc] = f2bf(acc[mt][nt][reg]);
        }
      }
    }
  }
}

// ---------------------------------------------------------------------------
// CSR build, phase 0: coarse histogram over NB buckets (LDS-staged)
// ---------------------------------------------------------------------------
__launch_bounds__(256)
__global__ void coarse_hist_kernel(const int* __restrict__ dst,
                                   int* __restrict__ chist) {
  __shared__ int h[NB];
  int t = threadIdx.x;
  if (t < NB) h[t] = 0;
  __syncthreads();
  int base = blockIdx.x * CT;
#pragma unroll
  for (int k = 0; k < 16; k++) {
    int e = base + t + k * 256;
    if (e < N_EDGES) atomicAdd(&h[dst[e] >> BSH], 1);
  }
  __syncthreads();
  if (t < NB && h[t]) atomicAdd(&chist[t], h[t]);
}

// ---------------------------------------------------------------------------
// phase 0b: exclusive scan of NB bucket counts; init bucket cursors
// ---------------------------------------------------------------------------
__launch_bounds__(128)
__global__ void coarse_scan_kernel(const int* __restrict__ chist,
                                   int* __restrict__ coff,
                                   int* __restrict__ bcur) {
  __shared__ int lds[128];
  int t = threadIdx.x;
  int v = (t < NB) ? chist[t] : 0;
  lds[t] = v;
  __syncthreads();
  int x = v;
  for (int ofs = 1; ofs < 128; ofs <<= 1) {
    int y = (t >= ofs) ? lds[t - ofs] : 0;
    __syncthreads();
    x += y;
    lds[t] = x;
    __syncthreads();
  }
  if (t < NB) {
    int o = x - v;
    coff[t] = o;
    bcur[t] = o;
  }
  if (t == NB) coff[NB] = N_EDGES;
}

// ---------------------------------------------------------------------------
// phase 1: partition edges into NB coarse buckets (LDS-staged runs)
// ---------------------------------------------------------------------------
__launch_bounds__(256)
__global__ void coarse_part_kernel(const int* __restrict__ src,
                                   const int* __restrict__ dst,
                                   const float* __restrict__ ew,
                                   int* __restrict__ bcur,
                                   int2* __restrict__ part) {
  __shared__ int hist[NB], start[NB], cur[NB], gbase[NB];
  __shared__ int sc[128];
  __shared__ int2 stage[CT];
  int t = threadIdx.x;
  if (t < NB) hist[t] = 0;
  __syncthreads();
  int base = blockIdx.x * CT;
#pragma unroll
  for (int k = 0; k < 16; k++) {
    int e = base + t + k * 256;
    if (e < N_EDGES) atomicAdd(&hist[dst[e] >> BSH], 1);
  }
  __syncthreads();
  int v = (t < NB) ? hist[t] : 0;
  if (t < 128) sc[t] = v;
  __syncthreads();
  int x = v;
  for (int ofs = 1; ofs < 128; ofs <<= 1) {
    int y = (t >= ofs && t < 128) ? sc[t - ofs] : 0;
    __syncthreads();
    if (t < 128) { x += y; sc[t] = x; }
    __syncthreads();
  }
  if (t < NB) {
    int st = x - v;
    start[t] = st;
    cur[t] = st;
    gbase[t] = atomicAdd(&bcur[t], hist[t]);
  }
  __syncthreads();
#pragma unroll
  for (int k = 0; k < 16; k++) {
    int e = base + t + k * 256;
    if (e < N_EDGES) {
      int d = dst[e];
      int b = d >> BSH;
      int lp = atomicAdd(&cur[b], 1);
      stage[lp] = make_int2((src[e] << 16) | d, __float_as_int(ew[e]));
    }
  }
  __syncthreads();
  int nedge = min(CT, N_EDGES - base);
  for (int i = t; i < nedge; i += 256) {
    int2 e = stage[i];
    int b = (e.x & 0xffff) >> BSH;
    part[gbase[b] + (i - start[b])] = e;
  }
}

// ---------------------------------------------------------------------------
// phase 2: per-bucket fine sort -> off[] + dst-sorted edata
// ---------------------------------------------------------------------------
__launch_bounds__(256)
__global__ void fine_kernel(const int* __restrict__ coff,
                            const int2* __restrict__ part,
                            int* __restrict__ off,
                            int2* __restrict__ edata) {
  __shared__ int nh[512];
  __shared__ int sc[256];
  int t = threadIdx.x;
  int b = blockIdx.x;
  int beg = coff[b], end = coff[b + 1];
  int nb = b << BSH;
  nh[t] = 0;
  nh[t + 256] = 0;
  __syncthreads();
  for (int i = beg + t; i < end; i += 256) {
    int d = part[i].x & 0xffff;
    atomicAdd(&nh[d - nb], 1);
  }
  __syncthreads();
  int a0 = nh[2 * t], a1 = nh[2 * t + 1];
  int s = a0 + a1;
  sc[t] = s;
  __syncthreads();
  int x = s;
  for (int ofs = 1; ofs < 256; ofs <<= 1) {
    int y = (t >= ofs) ? sc[t - ofs] : 0;
    __syncthreads();
    x += y;
    sc[t] = x;
    __syncthreads();
  }
  int pairExcl = x - s;
  int e0 = beg + pairExcl;
  int e1 = beg + pairExcl + a0;
  __syncthreads();
  nh[2 * t] = e0;
  nh[2 * t + 1] = e1;
  int g0 = nb + 2 * t, g1 = nb + 2 * t + 1;
  if (g0 <= N_NODES) off[g0] = e0;
  if (g1 <= N_NODES) off[g1] = e1;
  __syncthreads();
  for (int i = beg + t; i < end; i += 256) {
    int2 e = part[i];
    int d = e.x & 0xffff;
    int pos = atomicAdd(&nh[d - nb], 1);
    edata[pos] = make_int2((int)(((unsigned)e.x) >> 16), e.y);
  }
}

// ---------------------------------------------------------------------------
// Gather 1: agg[n][:] = sum_{j in CSR[n]} bf2f(XWb[src_j][:]) * w_j
// ---------------------------------------------------------------------------
__launch_bounds__(256)
__global__ void gather1_kernel(const unsigned short* __restrict__ XWb,
                               const int* __restrict__ off,
                               const int2* __restrict__ edata,
                               float* __restrict__ agg) {
  int gw = (int)((blockIdx.x * blockDim.x + threadIdx.x) >> 6);
  if (gw >= N_NODES) return;
  int lane = threadIdx.x & 63;
  int half = lane >> 5;
  int col4 = lane & 31;
  int beg = off[gw], end = off[gw + 1];
  f32x4 acc = (f32x4){0.f, 0.f, 0.f, 0.f};
  int j = beg + half;
  for (; j + 2 < end; j += 4) {
    int2 e0 = edata[j];
    int2 e1 = edata[j + 2];
    ushort4v r0 = *(const ushort4v*)(XWb + (size_t)e0.x * NHID + col4 * 4);
    ushort4v r1 = *(const ushort4v*)(XWb + (size_t)e1.x * NHID + col4 * 4);
    float w0 = __int_as_float(e0.y);
    float w1 = __int_as_float(e1.y);
    acc.x += bf2f(r0.x) * w0; acc.y += bf2f(r0.y) * w0;
    acc.z += bf2f(r0.z) * w0; acc.w += bf2f(r0.w) * w0;
    acc.x += bf2f(r1.x) * w1; acc.y += bf2f(r1.y) * w1;
    acc.z += bf2f(r1.z) * w1; acc.w += bf2f(r1.w) * w1;
  }
  if (j < end) {
    int2 e0 = edata[j];
    ushort4v r0 = *(const ushort4v*)(XWb + (size_t)e0.x * NHID + col4 * 4);
    float w0 = __int_as_float(e0.y);
    acc.x += bf2f(r0.x) * w0; acc.y += bf2f(r0.y) * w0;
    acc.z += bf2f(r0.z) * w0; acc.w += bf2f(r0.w) * w0;
  }
  acc.x += __shfl_down(acc.x, 32, 64);
  acc.y += __shfl_down(acc.y, 32, 64);
  acc.z += __shfl_down(acc.z, 32, 64);
  acc.w += __shfl_down(acc.w, 32, 64);
  if (lane < 32) {
    float4 o; o.x = acc.x; o.y = acc.y; o.z = acc.z; o.w = acc.w;
    *(float4*)(agg + (size_t)gw * NHID + col4 * 4) = o;
  }
}

// ---------------------------------------------------------------------------
// Gather 2: out_mu[n] = bmu + sum bf2f(Tb[src][0:64])*w ; out_lv likewise
// ---------------------------------------------------------------------------
__launch_bounds__(256)
__global__ void gather2_kernel(const unsigned short* __restrict__ Tb,
                               const int* __restrict__ off,
                               const int2* __restrict__ edata,
                               const float* __restrict__ bmu,
                               const float* __restrict__ blv,
                               float* __restrict__ out) {
  int gw = (int)((blockIdx.x * blockDim.x + threadIdx.x) >> 6);
  if (gw >= N_NODES) return;
  int lane = threadIdx.x & 63;
  int half = lane >> 5;
  int col4 = lane & 31;
  int beg = off[gw], end = off[gw + 1];
  f32x4 acc = (f32x4){0.f, 0.f, 0.f, 0.f};
  int j = beg + half;
  for (; j + 2 < end; j += 4) {
    int2 e0 = edata[j];
    int2 e1 = edata[j + 2];
    ushort4v r0 = *(const ushort4v*)(Tb + (size_t)e0.x * NHID + col4 * 4);
    ushort4v r1 = *(const ushort4v*)(Tb + (size_t)e1.x * NHID + col4 * 4);
    float w0 = __int_as_float(e0.y);
    float w1 = __int_as_float(e1.y);
    acc.x += bf2f(r0.x) * w0; acc.y += bf2f(r0.y) * w0;
    acc.z += bf2f(r0.z) * w0; acc.w += bf2f(r0.w) * w0;
    acc.x += bf2f(r1.x) * w1; acc.y += bf2f(r1.y) * w1;
    acc.z += bf2f(r1.z) * w1; acc.w += bf2f(r1.w) * w1;
  }
  if (j < end) {
    int2 e0 = edata[j];
    ushort4v r0 = *(const ushort4v*)(Tb + (size_t)e0.x * NHID + col4 * 4);
    float w0 = __int_as_float(e0.y);
    acc.x += bf2f(r0.x) * w0; acc.y += bf2f(r0.y) * w0;
    acc.z += bf2f(r0.z) * w0; acc.w += bf2f(r0.w) * w0;
  }
  acc.x += __shfl_down(acc.x, 32, 64);
  acc.y += __shfl_down(acc.y, 32, 64);
  acc.z += __shfl_down(acc.z, 32, 64);
  acc.w += __shfl_down(acc.w, 32, 64);
  if (lane < 16) {
    float4 bb = *(const float4*)(bmu + col4 * 4);
    float4 o; o.x = acc.x + bb.x; o.y = acc.y + bb.y;
    o.z = acc.z + bb.z; o.w = acc.w + bb.w;
    *(float4*)(out + (size_t)gw * LATENT + col4 * 4) = o;
  } else if (lane < 32) {
    int c = col4 - 16;
    float4 bb = *(const float4*)(blv + c * 4);
    float4 o; o.x = acc.x + bb.x; o.y = acc.y + bb.y;
    o.z = acc.z + bb.z; o.w = acc.w + bb.w;
    *(float4*)(out + (size_t)N_NODES * LATENT + (size_t)gw * LATENT + c * 4) = o;
  }
}

extern "C" void kernel_launch(void* const* d_in, const int* in_sizes, int n_in,
                              void* d_out, int out_size, void* d_ws, size_t ws_size,
                              hipStream_t stream) {
  const float* x   = (const float*)d_in[0];
  const int*   src = (const int*)d_in[1];
  const int*   dst = (const int*)d_in[2];
  const float* ew  = (const float*)d_in[3];
  const float* W1  = (const float*)d_in[4];
  const float* b1  = (const float*)d_in[5];
  const float* Wmu = (const float*)d_in[6];
  const float* bmu = (const float*)d_in[7];
  const float* Wlv = (const float*)d_in[8];
  const float* blv = (const float*)d_in[9];
  float* out = (float*)d_out;

  // workspace layout:
  unsigned short* bufb = (unsigned short*)d_ws;            // XWb then Tb (12.8MB)
  float* agg1 = (float*)(bufb + (size_t)N_NODES * NHID);   // 25.6MB
  int2* part  = (int2*)(agg1 + (size_t)N_NODES * NHID);    // 6.4MB
  int2* edata = part + N_EDGES;                            // 6.4MB
  int* off    = (int*)(edata + N_EDGES);                   // 50001 -> pad 50048
  int* chist  = off + 50048;                               // pad 128
  int* coff   = chist + 128;                               // pad 128
  int* bcur   = coff + 128;                                // pad 128
  unsigned short* W1T = (unsigned short*)(bcur + 128);     // 128*256 bf16 (64KB)
  unsigned short* WcT = W1T + 128 * NFEAT;                 // 128*128 bf16 (32KB)

  dim3 blk(256);
  int gemm_grid = (N_NODES + 63) / 64;         // 782
  int wave_grid = (N_NODES * 64 + 255) / 256;  // 12500

  hipMemsetAsync(chist, 0, 128 * sizeof(int), stream);

  prep_w_kernel<<<256, blk, 0, stream>>>(W1, Wmu, Wlv, W1T, WcT);
  gemm1_kernel<<<gemm_grid, blk, 0, stream>>>(x, W1T, bufb);
  coarse_hist_kernel<<<CBLK, blk, 0, stream>>>(dst, chist);
  coarse_scan_kernel<<<1, 128, 0, stream>>>(chist, coff, bcur);
  coarse_part_kernel<<<CBLK, blk, 0, stream>>>(src, dst, ew, bcur, part);
  fine_kernel<<<NB, blk, 0, stream>>>(coff, part, off, edata);

  gather1_kernel<<<wave_grid, blk, 0, stream>>>(bufb, off, edata, agg1);
  gemm2_kernel<<<gemm_grid, blk, 0, stream>>>(agg1, b1, WcT, bufb);
  gather2_kernel<<<wave_grid, blk, 0, stream>>>(bufb, off, edata, bmu, blv, out);
}

// Round 6
// 253.075 us; speedup vs baseline: 4.5077x; 1.0326x over previous
//
#include <hip/hip_runtime.h>
#include <hip/hip_bf16.h>

#define N_NODES 50000
#define N_EDGES 800000
#define NFEAT 256
#define NHID 128
#define LATENT 64
#define NB 98      // coarse buckets: dst >> 9 (512 nodes each; 98*512 = 50176)
#define BSH 9
#define CT 4096    // edges per coarse tile
#define CBLK 196   // ceil(800000/4096)

typedef __attribute__((ext_vector_type(8))) short bf16x8;
typedef __attribute__((ext_vector_type(4))) float f32x4;
typedef __attribute__((ext_vector_type(4))) short short4v;
typedef __attribute__((ext_vector_type(8))) short short8v;
typedef __attribute__((ext_vector_type(8))) unsigned short ushort8v;

__device__ inline unsigned short f2bf(float f) {
  union { float f; unsigned u; } c; c.f = f;
  unsigned r = (c.u + 0x7FFFu + ((c.u >> 16) & 1u)) >> 16;
  return (unsigned short)r;
}
__device__ inline float bf2f(unsigned short u) {
  union { unsigned u; float f; } c; c.u = ((unsigned)u) << 16;
  return c.f;
}

// ---------------------------------------------------------------------------
// Prep: W1T[n][k] = bf16(W1[k][n])  (128 x 256)
//       WcT[n][k] = bf16(concat(Wmu|Wlv)[k][n])  (128 x 128)
// ---------------------------------------------------------------------------
__launch_bounds__(256)
__global__ void prep_w_kernel(const float* __restrict__ W1,
                              const float* __restrict__ Wmu,
                              const float* __restrict__ Wlv,
                              unsigned short* __restrict__ W1T,
                              unsigned short* __restrict__ WcT) {
  int b = blockIdx.x;
  int t = threadIdx.x;
  if (b < 128) {
    W1T[b * NFEAT + t] = f2bf(W1[(size_t)t * NHID + b]);
  } else {
    int n = b - 128;
    if (t < NHID) {
      float v = (n < 64) ? Wmu[(size_t)t * LATENT + n]
                         : Wlv[(size_t)t * LATENT + (n - 64)];
      WcT[n * NHID + t] = f2bf(v);
    }
  }
}

// ---------------------------------------------------------------------------
// GEMM1: XWb[M=50000][128] = bf16( x[M][256] @ W1[256][128] )
// 64-row tile (grid 782); 4 waves each own a 32-col strip; B direct from W1T.
// ---------------------------------------------------------------------------
__launch_bounds__(256)
__global__ void gemm1_kernel(const float* __restrict__ X,
                             const unsigned short* __restrict__ W1T,
                             unsigned short* __restrict__ XWb) {
  __shared__ short A_lds[64][40];
  const int t = threadIdx.x;
  const int lane = t & 63;
  const int wave = t >> 6;
  const int row0 = blockIdx.x * 64;
  const int l15 = lane & 15, quad = lane >> 4;
  const int srow = t >> 2, skg = t & 3;

  f32x4 acc[4][2];
#pragma unroll
  for (int i = 0; i < 4; i++)
#pragma unroll
    for (int j = 0; j < 2; j++) acc[i][j] = (f32x4){0.f, 0.f, 0.f, 0.f};

  for (int k0 = 0; k0 < NFEAT; k0 += 32) {
    int gr = row0 + srow;
    float4 v0, v1;
    if (gr < N_NODES) {
      const float* p = X + (size_t)gr * NFEAT + k0 + skg * 8;
      v0 = *(const float4*)p;
      v1 = *(const float4*)(p + 4);
    } else {
      v0 = make_float4(0.f, 0.f, 0.f, 0.f);
      v1 = v0;
    }
    short8v s;
    s[0] = f2bf(v0.x); s[1] = f2bf(v0.y); s[2] = f2bf(v0.z); s[3] = f2bf(v0.w);
    s[4] = f2bf(v1.x); s[5] = f2bf(v1.y); s[6] = f2bf(v1.z); s[7] = f2bf(v1.w);
    __syncthreads();
    *(short8v*)&A_lds[srow][skg * 8] = s;
    __syncthreads();

    bf16x8 a[4], b[2];
#pragma unroll
    for (int mt = 0; mt < 4; mt++)
      a[mt] = *(const bf16x8*)&A_lds[mt * 16 + l15][quad * 8];
#pragma unroll
    for (int nt = 0; nt < 2; nt++) {
      int n = wave * 32 + nt * 16 + l15;
      b[nt] = *(const bf16x8*)(W1T + (size_t)n * NFEAT + k0 + quad * 8);
    }
#pragma unroll
    for (int mt = 0; mt < 4; mt++)
#pragma unroll
      for (int nt = 0; nt < 2; nt++)
        acc[mt][nt] = __builtin_amdgcn_mfma_f32_16x16x32_bf16(a[mt], b[nt], acc[mt][nt], 0, 0, 0);
  }
#pragma unroll
  for (int mt = 0; mt < 4; mt++) {
#pragma unroll
    for (int reg = 0; reg < 4; reg++) {
      int gr = row0 + mt * 16 + quad * 4 + reg;
      if (gr < N_NODES) {
#pragma unroll
        for (int nt = 0; nt < 2; nt++) {
          int gc = wave * 32 + nt * 16 + l15;
          XWb[(size_t)gr * NHID + gc] = f2bf(acc[mt][nt][reg]);
        }
      }
    }
  }
}

// ---------------------------------------------------------------------------
// GEMM2: Tb[M][128] = bf16( relu(bf2f(aggb)+b1) @ concat(Wmu|Wlv) )
// A input is bf16 aggb (written by gather1); bias+relu fused in staging.
// ---------------------------------------------------------------------------
__launch_bounds__(256)
__global__ void gemm2_kernel(const unsigned short* __restrict__ AGGb,
                             const float* __restrict__ b1,
                             const unsigned short* __restrict__ WcT,
                             unsigned short* __restrict__ Tb) {
  __shared__ short A_lds[64][40];
  const int t = threadIdx.x;
  const int lane = t & 63;
  const int wave = t >> 6;
  const int row0 = blockIdx.x * 64;
  const int l15 = lane & 15, quad = lane >> 4;
  const int srow = t >> 2, skg = t & 3;

  f32x4 acc[4][2];
#pragma unroll
  for (int i = 0; i < 4; i++)
#pragma unroll
    for (int j = 0; j < 2; j++) acc[i][j] = (f32x4){0.f, 0.f, 0.f, 0.f};

  for (int k0 = 0; k0 < NHID; k0 += 32) {
    int gr = row0 + srow;
    const float* bp = b1 + k0 + skg * 8;
    float4 bb0 = *(const float4*)bp;
    float4 bb1 = *(const float4*)(bp + 4);
    float bb[8] = {bb0.x, bb0.y, bb0.z, bb0.w, bb1.x, bb1.y, bb1.z, bb1.w};
    ushort8v raw;
    if (gr < N_NODES) {
      raw = *(const ushort8v*)(AGGb + (size_t)gr * NHID + k0 + skg * 8);
    } else {
#pragma unroll
      for (int k = 0; k < 8; k++) raw[k] = 0;
    }
    short8v s;
#pragma unroll
    for (int k = 0; k < 8; k++)
      s[k] = f2bf(fmaxf(bf2f(raw[k]) + bb[k], 0.f));
    __syncthreads();
    *(short8v*)&A_lds[srow][skg * 8] = s;
    __syncthreads();

    bf16x8 a[4], b[2];
#pragma unroll
    for (int mt = 0; mt < 4; mt++)
      a[mt] = *(const bf16x8*)&A_lds[mt * 16 + l15][quad * 8];
#pragma unroll
    for (int nt = 0; nt < 2; nt++) {
      int n = wave * 32 + nt * 16 + l15;
      b[nt] = *(const bf16x8*)(WcT + (size_t)n * NHID + k0 + quad * 8);
    }
#pragma unroll
    for (int mt = 0; mt < 4; mt++)
#pragma unroll
      for (int nt = 0; nt < 2; nt++)
        acc[mt][nt] = __builtin_amdgcn_mfma_f32_16x16x32_bf16(a[mt], b[nt], acc[mt][nt], 0, 0, 0);
  }
#pragma unroll
  for (int mt = 0; mt < 4; mt++) {
#pragma unroll
    for (int reg = 0; reg < 4; reg++) {
      int gr = row0 + mt * 16 + quad * 4 + reg;
      if (gr < N_NODES) {
#pragma unroll
        for (int nt = 0; nt < 2; nt++) {
          int gc = wave * 32 + nt * 16 + l15;
          Tb[(size_t)gr * NHID + gc] = f2bf(acc[mt][nt][reg]);
        }
      }
    }
  }
}

// ---------------------------------------------------------------------------
// CSR build, phase 0: coarse histogram over NB buckets (LDS-staged)
// ---------------------------------------------------------------------------
__launch_bounds__(256)
__global__ void coarse_hist_kernel(const int* __restrict__ dst,
                                   int* __restrict__ chist) {
  __shared__ int h[NB];
  int t = threadIdx.x;
  if (t < NB) h[t] = 0;
  __syncthreads();
  int base = blockIdx.x * CT;
#pragma unroll
  for (int k = 0; k < 16; k++) {
    int e = base + t + k * 256;
    if (e < N_EDGES) atomicAdd(&h[dst[e] >> BSH], 1);
  }
  __syncthreads();
  if (t < NB && h[t]) atomicAdd(&chist[t], h[t]);
}

// ---------------------------------------------------------------------------
// phase 0b: exclusive scan of NB bucket counts; init bucket cursors
// ---------------------------------------------------------------------------
__launch_bounds__(128)
__global__ void coarse_scan_kernel(const int* __restrict__ chist,
                                   int* __restrict__ coff,
                                   int* __restrict__ bcur) {
  __shared__ int lds[128];
  int t = threadIdx.x;
  int v = (t < NB) ? chist[t] : 0;
  lds[t] = v;
  __syncthreads();
  int x = v;
  for (int ofs = 1; ofs < 128; ofs <<= 1) {
    int y = (t >= ofs) ? lds[t - ofs] : 0;
    __syncthreads();
    x += y;
    lds[t] = x;
    __syncthreads();
  }
  if (t < NB) {
    int o = x - v;
    coff[t] = o;
    bcur[t] = o;
  }
  if (t == NB) coff[NB] = N_EDGES;
}

// ---------------------------------------------------------------------------
// phase 1: partition edges into NB coarse buckets (LDS-staged runs)
// ---------------------------------------------------------------------------
__launch_bounds__(256)
__global__ void coarse_part_kernel(const int* __restrict__ src,
                                   const int* __restrict__ dst,
                                   const float* __restrict__ ew,
                                   int* __restrict__ bcur,
                                   int2* __restrict__ part) {
  __shared__ int hist[NB], start[NB], cur[NB], gbase[NB];
  __shared__ int sc[128];
  __shared__ int2 stage[CT];
  int t = threadIdx.x;
  if (t < NB) hist[t] = 0;
  __syncthreads();
  int base = blockIdx.x * CT;
#pragma unroll
  for (int k = 0; k < 16; k++) {
    int e = base + t + k * 256;
    if (e < N_EDGES) atomicAdd(&hist[dst[e] >> BSH], 1);
  }
  __syncthreads();
  int v = (t < NB) ? hist[t] : 0;
  if (t < 128) sc[t] = v;
  __syncthreads();
  int x = v;
  for (int ofs = 1; ofs < 128; ofs <<= 1) {
    int y = (t >= ofs && t < 128) ? sc[t - ofs] : 0;
    __syncthreads();
    if (t < 128) { x += y; sc[t] = x; }
    __syncthreads();
  }
  if (t < NB) {
    int st = x - v;
    start[t] = st;
    cur[t] = st;
    gbase[t] = atomicAdd(&bcur[t], hist[t]);
  }
  __syncthreads();
#pragma unroll
  for (int k = 0; k < 16; k++) {
    int e = base + t + k * 256;
    if (e < N_EDGES) {
      int d = dst[e];
      int b = d >> BSH;
      int lp = atomicAdd(&cur[b], 1);
      stage[lp] = make_int2((src[e] << 16) | d, __float_as_int(ew[e]));
    }
  }
  __syncthreads();
  int nedge = min(CT, N_EDGES - base);
  for (int i = t; i < nedge; i += 256) {
    int2 e = stage[i];
    int b = (e.x & 0xffff) >> BSH;
    part[gbase[b] + (i - start[b])] = e;
  }
}

// ---------------------------------------------------------------------------
// phase 2: per-bucket fine sort -> off[] + dst-sorted edata
// ---------------------------------------------------------------------------
__launch_bounds__(256)
__global__ void fine_kernel(const int* __restrict__ coff,
                            const int2* __restrict__ part,
                            int* __restrict__ off,
                            int2* __restrict__ edata) {
  __shared__ int nh[512];
  __shared__ int sc[256];
  int t = threadIdx.x;
  int b = blockIdx.x;
  int beg = coff[b], end = coff[b + 1];
  int nb = b << BSH;
  nh[t] = 0;
  nh[t + 256] = 0;
  __syncthreads();
  for (int i = beg + t; i < end; i += 256) {
    int d = part[i].x & 0xffff;
    atomicAdd(&nh[d - nb], 1);
  }
  __syncthreads();
  int a0 = nh[2 * t], a1 = nh[2 * t + 1];
  int s = a0 + a1;
  sc[t] = s;
  __syncthreads();
  int x = s;
  for (int ofs = 1; ofs < 256; ofs <<= 1) {
    int y = (t >= ofs) ? sc[t - ofs] : 0;
    __syncthreads();
    x += y;
    sc[t] = x;
    __syncthreads();
  }
  int pairExcl = x - s;
  int e0 = beg + pairExcl;
  int e1 = beg + pairExcl + a0;
  __syncthreads();
  nh[2 * t] = e0;
  nh[2 * t + 1] = e1;
  int g0 = nb + 2 * t, g1 = nb + 2 * t + 1;
  if (g0 <= N_NODES) off[g0] = e0;
  if (g1 <= N_NODES) off[g1] = e1;
  __syncthreads();
  for (int i = beg + t; i < end; i += 256) {
    int2 e = part[i];
    int d = e.x & 0xffff;
    int pos = atomicAdd(&nh[d - nb], 1);
    edata[pos] = make_int2((int)(((unsigned)e.x) >> 16), e.y);
  }
}

// ---------------------------------------------------------------------------
// Gather 1: aggb[n][:] = bf16( sum_{j in CSR[n]} bf2f(XWb[src_j][:]) * w_j )
// One wave per node. QUARTER-wave per edge: 16 lanes x 16B (ushort8) = 256B
// row; 4 edges/wave concurrent, unroll x2 => 8 row loads in flight.
// ---------------------------------------------------------------------------
__launch_bounds__(256)
__global__ void gather1_kernel(const unsigned short* __restrict__ XWb,
                               const int* __restrict__ off,
                               const int2* __restrict__ edata,
                               unsigned short* __restrict__ aggb) {
  int gw = (int)((blockIdx.x * blockDim.x + threadIdx.x) >> 6);
  if (gw >= N_NODES) return;
  int lane = threadIdx.x & 63;
  int q = lane >> 4;    // quarter 0..3
  int c8 = lane & 15;   // col-group: cols 8*c8 .. 8*c8+7
  int beg = off[gw], end = off[gw + 1];
  float acc[8];
#pragma unroll
  for (int k = 0; k < 8; k++) acc[k] = 0.f;
  int j = beg + q;
  for (; j + 4 < end; j += 8) {
    int2 e0 = edata[j];
    int2 e1 = edata[j + 4];
    ushort8v r0 = *(const ushort8v*)(XWb + (size_t)e0.x * NHID + c8 * 8);
    ushort8v r1 = *(const ushort8v*)(XWb + (size_t)e1.x * NHID + c8 * 8);
    float w0 = __int_as_float(e0.y);
    float w1 = __int_as_float(e1.y);
#pragma unroll
    for (int k = 0; k < 8; k++) acc[k] += bf2f(r0[k]) * w0;
#pragma unroll
    for (int k = 0; k < 8; k++) acc[k] += bf2f(r1[k]) * w1;
  }
  if (j < end) {
    int2 e0 = edata[j];
    ushort8v r0 = *(const ushort8v*)(XWb + (size_t)e0.x * NHID + c8 * 8);
    float w0 = __int_as_float(e0.y);
#pragma unroll
    for (int k = 0; k < 8; k++) acc[k] += bf2f(r0[k]) * w0;
  }
  // fold quarters: q2/q3 -> q0/q1, then q1 -> q0
#pragma unroll
  for (int k = 0; k < 8; k++) {
    acc[k] += __shfl_down(acc[k], 32, 64);
    acc[k] += __shfl_down(acc[k], 16, 64);
  }
  if (lane < 16) {
    ushort8v st;
#pragma unroll
    for (int k = 0; k < 8; k++) st[k] = f2bf(acc[k]);
    *(ushort8v*)(aggb + (size_t)gw * NHID + c8 * 8) = st;
  }
}

// ---------------------------------------------------------------------------
// Gather 2: out_mu[n] = bmu + sum bf2f(Tb[src][0:64])*w ; out_lv cols 64:128.
// Same quarter-wave scheme; lanes 0..7 write mu, lanes 8..15 write lv.
// ---------------------------------------------------------------------------
__launch_bounds__(256)
__global__ void gather2_kernel(const unsigned short* __restrict__ Tb,
                               const int* __restrict__ off,
                               const int2* __restrict__ edata,
                               const float* __restrict__ bmu,
                               const float* __restrict__ blv,
                               float* __restrict__ out) {
  int gw = (int)((blockIdx.x * blockDim.x + threadIdx.x) >> 6);
  if (gw >= N_NODES) return;
  int lane = threadIdx.x & 63;
  int q = lane >> 4;
  int c8 = lane & 15;
  int beg = off[gw], end = off[gw + 1];
  float acc[8];
#pragma unroll
  for (int k = 0; k < 8; k++) acc[k] = 0.f;
  int j = beg + q;
  for (; j + 4 < end; j += 8) {
    int2 e0 = edata[j];
    int2 e1 = edata[j + 4];
    ushort8v r0 = *(const ushort8v*)(Tb + (size_t)e0.x * NHID + c8 * 8);
    ushort8v r1 = *(const ushort8v*)(Tb + (size_t)e1.x * NHID + c8 * 8);
    float w0 = __int_as_float(e0.y);
    float w1 = __int_as_float(e1.y);
#pragma unroll
    for (int k = 0; k < 8; k++) acc[k] += bf2f(r0[k]) * w0;
#pragma unroll
    for (int k = 0; k < 8; k++) acc[k] += bf2f(r1[k]) * w1;
  }
  if (j < end) {
    int2 e0 = edata[j];
    ushort8v r0 = *(const ushort8v*)(Tb + (size_t)e0.x * NHID + c8 * 8);
    float w0 = __int_as_float(e0.y);
#pragma unroll
    for (int k = 0; k < 8; k++) acc[k] += bf2f(r0[k]) * w0;
  }
#pragma unroll
  for (int k = 0; k < 8; k++) {
    acc[k] += __shfl_down(acc[k], 32, 64);
    acc[k] += __shfl_down(acc[k], 16, 64);
  }
  if (lane < 8) {
    // mu: cols 8*c8 .. 8*c8+7
    const float* bp = bmu + c8 * 8;
    float4 b0 = *(const float4*)bp;
    float4 b1v = *(const float4*)(bp + 4);
    float* op = out + (size_t)gw * LATENT + c8 * 8;
    float4 o0, o1;
    o0.x = acc[0] + b0.x; o0.y = acc[1] + b0.y;
    o0.z = acc[2] + b0.z; o0.w = acc[3] + b0.w;
    o1.x = acc[4] + b1v.x; o1.y = acc[5] + b1v.y;
    o1.z = acc[6] + b1v.z; o1.w = acc[7] + b1v.w;
    *(float4*)op = o0;
    *(float4*)(op + 4) = o1;
  } else if (lane < 16) {
    int c = c8 - 8;  // lv cols 8c..8c+7
    const float* bp = blv + c * 8;
    float4 b0 = *(const float4*)bp;
    float4 b1v = *(const float4*)(bp + 4);
    float* op = out + (size_t)N_NODES * LATENT + (size_t)gw * LATENT + c * 8;
    float4 o0, o1;
    o0.x = acc[0] + b0.x; o0.y = acc[1] + b0.y;
    o0.z = acc[2] + b0.z; o0.w = acc[3] + b0.w;
    o1.x = acc[4] + b1v.x; o1.y = acc[5] + b1v.y;
    o1.z = acc[6] + b1v.z; o1.w = acc[7] + b1v.w;
    *(float4*)op = o0;
    *(float4*)(op + 4) = o1;
  }
}

extern "C" void kernel_launch(void* const* d_in, const int* in_sizes, int n_in,
                              void* d_out, int out_size, void* d_ws, size_t ws_size,
                              hipStream_t stream) {
  const float* x   = (const float*)d_in[0];
  const int*   src = (const int*)d_in[1];
  const int*   dst = (const int*)d_in[2];
  const float* ew  = (const float*)d_in[3];
  const float* W1  = (const float*)d_in[4];
  const float* b1  = (const float*)d_in[5];
  const float* Wmu = (const float*)d_in[6];
  const float* bmu = (const float*)d_in[7];
  const float* Wlv = (const float*)d_in[8];
  const float* blv = (const float*)d_in[9];
  float* out = (float*)d_out;

  // workspace layout:
  unsigned short* bufb = (unsigned short*)d_ws;            // XWb then Tb (12.8MB)
  unsigned short* aggb = bufb + (size_t)N_NODES * NHID;    // bf16 agg (12.8MB)
  int2* part  = (int2*)(aggb + (size_t)N_NODES * NHID);    // 6.4MB
  int2* edata = part + N_EDGES;                            // 6.4MB
  int* off    = (int*)(edata + N_EDGES);                   // 50001 -> pad 50048
  int* chist  = off + 50048;                               // pad 128
  int* coff   = chist + 128;                               // pad 128
  int* bcur   = coff + 128;                                // pad 128
  unsigned short* W1T = (unsigned short*)(bcur + 128);     // 128*256 bf16
  unsigned short* WcT = W1T + 128 * NFEAT;                 // 128*128 bf16

  dim3 blk(256);
  int gemm_grid = (N_NODES + 63) / 64;         // 782
  int wave_grid = (N_NODES * 64 + 255) / 256;  // 12500

  hipMemsetAsync(chist, 0, 128 * sizeof(int), stream);

  prep_w_kernel<<<256, blk, 0, stream>>>(W1, Wmu, Wlv, W1T, WcT);
  gemm1_kernel<<<gemm_grid, blk, 0, stream>>>(x, W1T, bufb);
  coarse_hist_kernel<<<CBLK, blk, 0, stream>>>(dst, chist);
  coarse_scan_kernel<<<1, 128, 0, stream>>>(chist, coff, bcur);
  coarse_part_kernel<<<CBLK, blk, 0, stream>>>(src, dst, ew, bcur, part);
  fine_kernel<<<NB, blk, 0, stream>>>(coff, part, off, edata);

  gather1_kernel<<<wave_grid, blk, 0, stream>>>(bufb, off, edata, aggb);
  gemm2_kernel<<<gemm_grid, blk, 0, stream>>>(aggb, b1, WcT, bufb);
  gather2_kernel<<<wave_grid, blk, 0, stream>>>(bufb, off, edata, bmu, blv, out);
}

// Round 7
// 230.314 us; speedup vs baseline: 4.9532x; 1.0988x over previous
//
#include <hip/hip_runtime.h>
#include <hip/hip_bf16.h>

#define N_NODES 50000
#define N_EDGES 800000
#define NFEAT 256
#define NHID 128
#define LATENT 64
#define NB 98       // coarse buckets: dst >> 9 (512 nodes each; 98*512 = 50176)
#define BSH 9
#define CT 4096     // edges per coarse tile
#define CBLK 196    // ceil(800000/4096)
#define CAP 8960    // per-bucket capacity: mean 8192 + 8.5 sigma (~90)

typedef __attribute__((ext_vector_type(8))) short bf16x8;
typedef __attribute__((ext_vector_type(4))) float f32x4;
typedef __attribute__((ext_vector_type(8))) short short8v;
typedef __attribute__((ext_vector_type(8))) unsigned short ushort8v;

__device__ inline unsigned short f2bf(float f) {
  union { float f; unsigned u; } c; c.f = f;
  unsigned r = (c.u + 0x7FFFu + ((c.u >> 16) & 1u)) >> 16;
  return (unsigned short)r;
}
__device__ inline float bf2f(unsigned short u) {
  union { unsigned u; float f; } c; c.u = ((unsigned)u) << 16;
  return c.f;
}

// ---------------------------------------------------------------------------
// Prep: W1T[n][k]=bf16(W1[k][n]) (128x256); WcT[n][k]=bf16([Wmu|Wlv][k][n])
// (128x128). Block 256 zeroes the bucket cursors (replaces hipMemset).
// ---------------------------------------------------------------------------
__launch_bounds__(256)
__global__ void prep_w_kernel(const float* __restrict__ W1,
                              const float* __restrict__ Wmu,
                              const float* __restrict__ Wlv,
                              unsigned short* __restrict__ W1T,
                              unsigned short* __restrict__ WcT,
                              int* __restrict__ bcur) {
  int b = blockIdx.x;
  int t = threadIdx.x;
  if (b < 128) {
    W1T[b * NFEAT + t] = f2bf(W1[(size_t)t * NHID + b]);
  } else if (b < 256) {
    int n = b - 128;
    if (t < NHID) {
      float v = (n < 64) ? Wmu[(size_t)t * LATENT + n]
                         : Wlv[(size_t)t * LATENT + (n - 64)];
      WcT[n * NHID + t] = f2bf(v);
    }
  } else {
    if (t < 128) bcur[t] = 0;
  }
}

// ---------------------------------------------------------------------------
// GEMM1: XWb[50000][128] = bf16( x @ W1 ). 64-row tile, B direct from W1T.
// ---------------------------------------------------------------------------
__launch_bounds__(256)
__global__ void gemm1_kernel(const float* __restrict__ X,
                             const unsigned short* __restrict__ W1T,
                             unsigned short* __restrict__ XWb) {
  __shared__ short A_lds[64][40];
  const int t = threadIdx.x;
  const int lane = t & 63;
  const int wave = t >> 6;
  const int row0 = blockIdx.x * 64;
  const int l15 = lane & 15, quad = lane >> 4;
  const int srow = t >> 2, skg = t & 3;

  f32x4 acc[4][2];
#pragma unroll
  for (int i = 0; i < 4; i++)
#pragma unroll
    for (int j = 0; j < 2; j++) acc[i][j] = (f32x4){0.f, 0.f, 0.f, 0.f};

  for (int k0 = 0; k0 < NFEAT; k0 += 32) {
    int gr = row0 + srow;
    float4 v0, v1;
    if (gr < N_NODES) {
      const float* p = X + (size_t)gr * NFEAT + k0 + skg * 8;
      v0 = *(const float4*)p;
      v1 = *(const float4*)(p + 4);
    } else {
      v0 = make_float4(0.f, 0.f, 0.f, 0.f);
      v1 = v0;
    }
    short8v s;
    s[0] = f2bf(v0.x); s[1] = f2bf(v0.y); s[2] = f2bf(v0.z); s[3] = f2bf(v0.w);
    s[4] = f2bf(v1.x); s[5] = f2bf(v1.y); s[6] = f2bf(v1.z); s[7] = f2bf(v1.w);
    __syncthreads();
    *(short8v*)&A_lds[srow][skg * 8] = s;
    __syncthreads();

    bf16x8 a[4], b[2];
#pragma unroll
    for (int mt = 0; mt < 4; mt++)
      a[mt] = *(const bf16x8*)&A_lds[mt * 16 + l15][quad * 8];
#pragma unroll
    for (int nt = 0; nt < 2; nt++) {
      int n = wave * 32 + nt * 16 + l15;
      b[nt] = *(const bf16x8*)(W1T + (size_t)n * NFEAT + k0 + quad * 8);
    }
#pragma unroll
    for (int mt = 0; mt < 4; mt++)
#pragma unroll
      for (int nt = 0; nt < 2; nt++)
        acc[mt][nt] = __builtin_amdgcn_mfma_f32_16x16x32_bf16(a[mt], b[nt], acc[mt][nt], 0, 0, 0);
  }
#pragma unroll
  for (int mt = 0; mt < 4; mt++) {
#pragma unroll
    for (int reg = 0; reg < 4; reg++) {
      int gr = row0 + mt * 16 + quad * 4 + reg;
      if (gr < N_NODES) {
#pragma unroll
        for (int nt = 0; nt < 2; nt++) {
          int gc = wave * 32 + nt * 16 + l15;
          XWb[(size_t)gr * NHID + gc] = f2bf(acc[mt][nt][reg]);
        }
      }
    }
  }
}

// ---------------------------------------------------------------------------
// Single-pass coarse partition into capacity-padded buckets.
// Per block: LDS hist -> reserve bucket space (1 atomic/bucket) -> LDS-stage
// bucket-sorted -> coalesced run writes to part[b*CAP + ...].
// part entry: x=(src<<16)|dst, y=fp32 w.
// ---------------------------------------------------------------------------
__launch_bounds__(512)
__global__ void coarse_part_kernel(const int* __restrict__ src,
                                   const int* __restrict__ dst,
                                   const float* __restrict__ ew,
                                   int* __restrict__ bcur,
                                   int2* __restrict__ part) {
  __shared__ int hist[NB], start[NB], cur[NB], gbase[NB];
  __shared__ int sc[128];
  __shared__ int2 stage[CT];
  int t = threadIdx.x;
  if (t < NB) hist[t] = 0;
  __syncthreads();
  int base = blockIdx.x * CT;
#pragma unroll
  for (int k = 0; k < 8; k++) {
    int e = base + t + k * 512;
    if (e < N_EDGES) atomicAdd(&hist[dst[e] >> BSH], 1);
  }
  __syncthreads();
  int v = (t < NB) ? hist[t] : 0;
  if (t < 128) sc[t] = v;
  __syncthreads();
  int x = v;
  for (int ofs = 1; ofs < 128; ofs <<= 1) {
    int y = (t >= ofs && t < 128) ? sc[t - ofs] : 0;
    __syncthreads();
    if (t < 128) { x += y; sc[t] = x; }
    __syncthreads();
  }
  if (t < NB) {
    int st = x - v;
    start[t] = st;
    cur[t] = st;
    gbase[t] = atomicAdd(&bcur[t], hist[t]);
  }
  __syncthreads();
#pragma unroll
  for (int k = 0; k < 8; k++) {
    int e = base + t + k * 512;
    if (e < N_EDGES) {
      int d = dst[e];
      int b = d >> BSH;
      int lp = atomicAdd(&cur[b], 1);
      stage[lp] = make_int2((src[e] << 16) | d, __float_as_int(ew[e]));
    }
  }
  __syncthreads();
  int nedge = min(CT, N_EDGES - base);
  for (int i = t; i < nedge; i += 512) {
    int2 e = stage[i];
    int b = (e.x & 0xffff) >> BSH;
    part[(size_t)b * CAP + gbase[b] + (i - start[b])] = e;
  }
}

// ---------------------------------------------------------------------------
// Per-bucket fine sort -> offs[n]=(beg,end) + dst-sorted packed edata
// (4B: (src<<16)|bf16(w)). One block (512 thr) per bucket; node t owned by
// thread t. All coords in padded bucket space.
// ---------------------------------------------------------------------------
__launch_bounds__(512)
__global__ void fine_kernel(const int* __restrict__ bcur,
                            const int2* __restrict__ part,
                            int2* __restrict__ offs,
                            unsigned int* __restrict__ edata) {
  __shared__ int nh[512];
  __shared__ int sc[512];
  int t = threadIdx.x;
  int b = blockIdx.x;
  int base = b * CAP;
  int cnt = bcur[b];
  int nb = b << BSH;
  nh[t] = 0;
  __syncthreads();
  for (int i = t; i < cnt; i += 512) {
    int d = part[base + i].x & 0xffff;
    atomicAdd(&nh[d - nb], 1);
  }
  __syncthreads();
  int v = nh[t];
  sc[t] = v;
  __syncthreads();
  int x = v;
  for (int ofs = 1; ofs < 512; ofs <<= 1) {
    int y = (t >= ofs) ? sc[t - ofs] : 0;
    __syncthreads();
    x += y;
    sc[t] = x;
    __syncthreads();
  }
  int beg = base + (x - v);
  offs[nb + t] = make_int2(beg, beg + v);
  nh[t] = beg;
  __syncthreads();
  for (int i = t; i < cnt; i += 512) {
    int2 e = part[base + i];
    int d = e.x & 0xffff;
    int pos = atomicAdd(&nh[d - nb], 1);
    edata[pos] = (unsigned)(e.x & 0xffff0000) | (unsigned)f2bf(__int_as_float(e.y));
  }
}

// ---------------------------------------------------------------------------
// FUSED gather1 + GEMM2. One block per 64-node tile:
//  phase 1: wave w gathers rows w*16..w*16+15 (quarter-wave per edge) and
//           writes relu(sum + b1) as bf16 straight into the MFMA A-tile.
//  phase 2: K=128 MFMA loop, B direct from WcT; epilogue -> Tb.
// ---------------------------------------------------------------------------
__launch_bounds__(256)
__global__ void g1gemm2_kernel(const unsigned short* __restrict__ XWb,
                               const int2* __restrict__ offs,
                               const unsigned int* __restrict__ edata,
                               const float* __restrict__ b1,
                               const unsigned short* __restrict__ WcT,
                               unsigned short* __restrict__ Tb) {
  __shared__ short A_lds[64][136];  // 128 cols + 8 pad (breaks 256B stride)
  const int t = threadIdx.x;
  const int lane = t & 63;
  const int wave = t >> 6;
  const int row0 = blockIdx.x * 64;
  const int l15 = lane & 15, quad = lane >> 4;  // quad doubles as quarter id

  float bb[8];
#pragma unroll
  for (int k = 0; k < 8; k++) bb[k] = b1[l15 * 8 + k];

  // phase 1: gather 16 rows per wave
  for (int r = 0; r < 16; r++) {
    int row = wave * 16 + r;
    int gw = row0 + row;
    float acc[8];
#pragma unroll
    for (int k = 0; k < 8; k++) acc[k] = 0.f;
    if (gw < N_NODES) {
      int2 oo = offs[gw];
      int j = oo.x + quad;
      int end = oo.y;
      for (; j + 4 < end; j += 8) {
        unsigned e0 = edata[j];
        unsigned e1 = edata[j + 4];
        ushort8v r0 = *(const ushort8v*)(XWb + (size_t)(e0 >> 16) * NHID + l15 * 8);
        ushort8v r1 = *(const ushort8v*)(XWb + (size_t)(e1 >> 16) * NHID + l15 * 8);
        float w0 = bf2f((unsigned short)(e0 & 0xffffu));
        float w1 = bf2f((unsigned short)(e1 & 0xffffu));
#pragma unroll
        for (int k = 0; k < 8; k++) acc[k] += bf2f(r0[k]) * w0;
#pragma unroll
        for (int k = 0; k < 8; k++) acc[k] += bf2f(r1[k]) * w1;
      }
      if (j < end) {
        unsigned e0 = edata[j];
        ushort8v r0 = *(const ushort8v*)(XWb + (size_t)(e0 >> 16) * NHID + l15 * 8);
        float w0 = bf2f((unsigned short)(e0 & 0xffffu));
#pragma unroll
        for (int k = 0; k < 8; k++) acc[k] += bf2f(r0[k]) * w0;
      }
    }
#pragma unroll
    for (int k = 0; k < 8; k++) {
      acc[k] += __shfl_down(acc[k], 32, 64);
      acc[k] += __shfl_down(acc[k], 16, 64);
    }
    if (lane < 16) {
      short8v s;
#pragma unroll
      for (int k = 0; k < 8; k++) s[k] = (short)f2bf(fmaxf(acc[k] + bb[k], 0.f));
      *(short8v*)&A_lds[row][l15 * 8] = s;
    }
  }
  __syncthreads();

  // phase 2: MFMA over K=128 (A fully resident in LDS; no more barriers)
  f32x4 acc2[4][2];
#pragma unroll
  for (int i = 0; i < 4; i++)
#pragma unroll
    for (int j = 0; j < 2; j++) acc2[i][j] = (f32x4){0.f, 0.f, 0.f, 0.f};

#pragma unroll
  for (int k0 = 0; k0 < NHID; k0 += 32) {
    bf16x8 a[4], b[2];
#pragma unroll
    for (int mt = 0; mt < 4; mt++)
      a[mt] = *(const bf16x8*)&A_lds[mt * 16 + l15][k0 + quad * 8];
#pragma unroll
    for (int nt = 0; nt < 2; nt++) {
      int n = wave * 32 + nt * 16 + l15;
      b[nt] = *(const bf16x8*)(WcT + (size_t)n * NHID + k0 + quad * 8);
    }
#pragma unroll
    for (int mt = 0; mt < 4; mt++)
#pragma unroll
      for (int nt = 0; nt < 2; nt++)
        acc2[mt][nt] = __builtin_amdgcn_mfma_f32_16x16x32_bf16(a[mt], b[nt], acc2[mt][nt], 0, 0, 0);
  }
#pragma unroll
  for (int mt = 0; mt < 4; mt++) {
#pragma unroll
    for (int reg = 0; reg < 4; reg++) {
      int gr = row0 + mt * 16 + quad * 4 + reg;
      if (gr < N_NODES) {
#pragma unroll
        for (int nt = 0; nt < 2; nt++) {
          int gc = wave * 32 + nt * 16 + l15;
          Tb[(size_t)gr * NHID + gc] = f2bf(acc2[mt][nt][reg]);
        }
      }
    }
  }
}

// ---------------------------------------------------------------------------
// Gather 2: out_mu[n] = bmu + sum bf2f(Tb[src][0:64])*w ; out_lv cols 64:128.
// Quarter-wave per edge, packed 4B edata.
// ---------------------------------------------------------------------------
__launch_bounds__(256)
__global__ void gather2_kernel(const unsigned short* __restrict__ Tb,
                               const int2* __restrict__ offs,
                               const unsigned int* __restrict__ edata,
                               const float* __restrict__ bmu,
                               const float* __restrict__ blv,
                               float* __restrict__ out) {
  int gw = (int)((blockIdx.x * blockDim.x + threadIdx.x) >> 6);
  if (gw >= N_NODES) return;
  int lane = threadIdx.x & 63;
  int q = lane >> 4;
  int c8 = lane & 15;
  int2 oo = offs[gw];
  int end = oo.y;
  float acc[8];
#pragma unroll
  for (int k = 0; k < 8; k++) acc[k] = 0.f;
  int j = oo.x + q;
  for (; j + 4 < end; j += 8) {
    unsigned e0 = edata[j];
    unsigned e1 = edata[j + 4];
    ushort8v r0 = *(const ushort8v*)(Tb + (size_t)(e0 >> 16) * NHID + c8 * 8);
    ushort8v r1 = *(const ushort8v*)(Tb + (size_t)(e1 >> 16) * NHID + c8 * 8);
    float w0 = bf2f((unsigned short)(e0 & 0xffffu));
    float w1 = bf2f((unsigned short)(e1 & 0xffffu));
#pragma unroll
    for (int k = 0; k < 8; k++) acc[k] += bf2f(r0[k]) * w0;
#pragma unroll
    for (int k = 0; k < 8; k++) acc[k] += bf2f(r1[k]) * w1;
  }
  if (j < end) {
    unsigned e0 = edata[j];
    ushort8v r0 = *(const ushort8v*)(Tb + (size_t)(e0 >> 16) * NHID + c8 * 8);
    float w0 = bf2f((unsigned short)(e0 & 0xffffu));
#pragma unroll
    for (int k = 0; k < 8; k++) acc[k] += bf2f(r0[k]) * w0;
  }
#pragma unroll
  for (int k = 0; k < 8; k++) {
    acc[k] += __shfl_down(acc[k], 32, 64);
    acc[k] += __shfl_down(acc[k], 16, 64);
  }
  if (lane < 8) {
    const float* bp = bmu + c8 * 8;
    float4 b0 = *(const float4*)bp;
    float4 b1v = *(const float4*)(bp + 4);
    float* op = out + (size_t)gw * LATENT + c8 * 8;
    float4 o0, o1;
    o0.x = acc[0] + b0.x; o0.y = acc[1] + b0.y;
    o0.z = acc[2] + b0.z; o0.w = acc[3] + b0.w;
    o1.x = acc[4] + b1v.x; o1.y = acc[5] + b1v.y;
    o1.z = acc[6] + b1v.z; o1.w = acc[7] + b1v.w;
    *(float4*)op = o0;
    *(float4*)(op + 4) = o1;
  } else if (lane < 16) {
    int c = c8 - 8;
    const float* bp = blv + c * 8;
    float4 b0 = *(const float4*)bp;
    float4 b1v = *(const float4*)(bp + 4);
    float* op = out + (size_t)N_NODES * LATENT + (size_t)gw * LATENT + c * 8;
    float4 o0, o1;
    o0.x = acc[0] + b0.x; o0.y = acc[1] + b0.y;
    o0.z = acc[2] + b0.z; o0.w = acc[3] + b0.w;
    o1.x = acc[4] + b1v.x; o1.y = acc[5] + b1v.y;
    o1.z = acc[6] + b1v.z; o1.w = acc[7] + b1v.w;
    *(float4*)op = o0;
    *(float4*)(op + 4) = o1;
  }
}

extern "C" void kernel_launch(void* const* d_in, const int* in_sizes, int n_in,
                              void* d_out, int out_size, void* d_ws, size_t ws_size,
                              hipStream_t stream) {
  const float* x   = (const float*)d_in[0];
  const int*   src = (const int*)d_in[1];
  const int*   dst = (const int*)d_in[2];
  const float* ew  = (const float*)d_in[3];
  const float* W1  = (const float*)d_in[4];
  const float* b1  = (const float*)d_in[5];
  const float* Wmu = (const float*)d_in[6];
  const float* bmu = (const float*)d_in[7];
  const float* Wlv = (const float*)d_in[8];
  const float* blv = (const float*)d_in[9];
  float* out = (float*)d_out;

  // workspace layout (8B-aligned segments):
  unsigned short* XWb = (unsigned short*)d_ws;             // 12.8 MB
  unsigned short* Tbb = XWb + (size_t)N_NODES * NHID;      // 12.8 MB
  int2* part = (int2*)(Tbb + (size_t)N_NODES * NHID);      // 98*8960*8 = 7.0 MB
  unsigned int* edata = (unsigned int*)(part + (size_t)NB * CAP);  // 3.5 MB
  int2* offs = (int2*)(edata + (size_t)NB * CAP);          // 50176*8 = 401 KB
  int* bcur  = (int*)(offs + 50176);                       // 128 ints
  unsigned short* W1T = (unsigned short*)(bcur + 128);     // 128*256 bf16
  unsigned short* WcT = W1T + 128 * NFEAT;                 // 128*128 bf16

  dim3 blk(256);
  int gemm_grid = (N_NODES + 63) / 64;         // 782
  int wave_grid = (N_NODES * 64 + 255) / 256;  // 12500

  prep_w_kernel<<<257, blk, 0, stream>>>(W1, Wmu, Wlv, W1T, WcT, bcur);
  gemm1_kernel<<<gemm_grid, blk, 0, stream>>>(x, W1T, XWb);
  coarse_part_kernel<<<CBLK, dim3(512), 0, stream>>>(src, dst, ew, bcur, part);
  fine_kernel<<<NB, dim3(512), 0, stream>>>(bcur, part, offs, edata);
  g1gemm2_kernel<<<gemm_grid, blk, 0, stream>>>(XWb, offs, edata, b1, WcT, Tbb);
  gather2_kernel<<<wave_grid, blk, 0, stream>>>(Tbb, offs, edata, bmu, blv, out);
}

// Round 8
// 226.662 us; speedup vs baseline: 5.0330x; 1.0161x over previous
//
#include <hip/hip_runtime.h>
#include <hip/hip_bf16.h>

#define N_NODES 50000
#define N_EDGES 800000
#define NFEAT 256
#define NHID 128
#define LATENT 64
#define NB 98       // coarse buckets: dst >> 9 (512 nodes each; 98*512 = 50176)
#define BSH 9
#define CT 4096     // edges per coarse tile
#define CBLK 196    // ceil(800000/4096)
#define CAP 8960    // per-bucket capacity: mean 8192 + 8.5 sigma (~90)

typedef __attribute__((ext_vector_type(8))) short bf16x8;
typedef __attribute__((ext_vector_type(4))) float f32x4;
typedef __attribute__((ext_vector_type(8))) short short8v;
typedef __attribute__((ext_vector_type(8))) unsigned short ushort8v;

__device__ inline unsigned short f2bf(float f) {
  union { float f; unsigned u; } c; c.f = f;
  unsigned r = (c.u + 0x7FFFu + ((c.u >> 16) & 1u)) >> 16;
  return (unsigned short)r;
}
__device__ inline float bf2f(unsigned short u) {
  union { unsigned u; float f; } c; c.u = ((unsigned)u) << 16;
  return c.f;
}

// ---------------------------------------------------------------------------
// Prep: W1T[n][k]=bf16(W1[k][n]) (128x256); WcT[n][k]=bf16([Wmu|Wlv][k][n])
// (128x128). Block 256 zeroes the bucket cursors.
// ---------------------------------------------------------------------------
__launch_bounds__(256)
__global__ void prep_w_kernel(const float* __restrict__ W1,
                              const float* __restrict__ Wmu,
                              const float* __restrict__ Wlv,
                              unsigned short* __restrict__ W1T,
                              unsigned short* __restrict__ WcT,
                              int* __restrict__ bcur) {
  int b = blockIdx.x;
  int t = threadIdx.x;
  if (b < 128) {
    W1T[b * NFEAT + t] = f2bf(W1[(size_t)t * NHID + b]);
  } else if (b < 256) {
    int n = b - 128;
    if (t < NHID) {
      float v = (n < 64) ? Wmu[(size_t)t * LATENT + n]
                         : Wlv[(size_t)t * LATENT + (n - 64)];
      WcT[n * NHID + t] = f2bf(v);
    }
  } else {
    if (t < 128) bcur[t] = 0;
  }
}

// ---------------------------------------------------------------------------
// GEMM1: XWb[50000][128] = bf16( x @ W1 ). 64-row tile, B direct from W1T.
// ---------------------------------------------------------------------------
__launch_bounds__(256)
__global__ void gemm1_kernel(const float* __restrict__ X,
                             const unsigned short* __restrict__ W1T,
                             unsigned short* __restrict__ XWb) {
  __shared__ short A_lds[64][40];
  const int t = threadIdx.x;
  const int lane = t & 63;
  const int wave = t >> 6;
  const int row0 = blockIdx.x * 64;
  const int l15 = lane & 15, quad = lane >> 4;
  const int srow = t >> 2, skg = t & 3;

  f32x4 acc[4][2];
#pragma unroll
  for (int i = 0; i < 4; i++)
#pragma unroll
    for (int j = 0; j < 2; j++) acc[i][j] = (f32x4){0.f, 0.f, 0.f, 0.f};

  for (int k0 = 0; k0 < NFEAT; k0 += 32) {
    int gr = row0 + srow;
    float4 v0, v1;
    if (gr < N_NODES) {
      const float* p = X + (size_t)gr * NFEAT + k0 + skg * 8;
      v0 = *(const float4*)p;
      v1 = *(const float4*)(p + 4);
    } else {
      v0 = make_float4(0.f, 0.f, 0.f, 0.f);
      v1 = v0;
    }
    short8v s;
    s[0] = f2bf(v0.x); s[1] = f2bf(v0.y); s[2] = f2bf(v0.z); s[3] = f2bf(v0.w);
    s[4] = f2bf(v1.x); s[5] = f2bf(v1.y); s[6] = f2bf(v1.z); s[7] = f2bf(v1.w);
    __syncthreads();
    *(short8v*)&A_lds[srow][skg * 8] = s;
    __syncthreads();

    bf16x8 a[4], b[2];
#pragma unroll
    for (int mt = 0; mt < 4; mt++)
      a[mt] = *(const bf16x8*)&A_lds[mt * 16 + l15][quad * 8];
#pragma unroll
    for (int nt = 0; nt < 2; nt++) {
      int n = wave * 32 + nt * 16 + l15;
      b[nt] = *(const bf16x8*)(W1T + (size_t)n * NFEAT + k0 + quad * 8);
    }
#pragma unroll
    for (int mt = 0; mt < 4; mt++)
#pragma unroll
      for (int nt = 0; nt < 2; nt++)
        acc[mt][nt] = __builtin_amdgcn_mfma_f32_16x16x32_bf16(a[mt], b[nt], acc[mt][nt], 0, 0, 0);
  }
#pragma unroll
  for (int mt = 0; mt < 4; mt++) {
#pragma unroll
    for (int reg = 0; reg < 4; reg++) {
      int gr = row0 + mt * 16 + quad * 4 + reg;
      if (gr < N_NODES) {
#pragma unroll
        for (int nt = 0; nt < 2; nt++) {
          int gc = wave * 32 + nt * 16 + l15;
          XWb[(size_t)gr * NHID + gc] = f2bf(acc[mt][nt][reg]);
        }
      }
    }
  }
}

// ---------------------------------------------------------------------------
// Single-pass coarse partition into capacity-padded buckets.
// ---------------------------------------------------------------------------
__launch_bounds__(512)
__global__ void coarse_part_kernel(const int* __restrict__ src,
                                   const int* __restrict__ dst,
                                   const float* __restrict__ ew,
                                   int* __restrict__ bcur,
                                   int2* __restrict__ part) {
  __shared__ int hist[NB], start[NB], cur[NB], gbase[NB];
  __shared__ int sc[128];
  __shared__ int2 stage[CT];
  int t = threadIdx.x;
  if (t < NB) hist[t] = 0;
  __syncthreads();
  int base = blockIdx.x * CT;
#pragma unroll
  for (int k = 0; k < 8; k++) {
    int e = base + t + k * 512;
    if (e < N_EDGES) atomicAdd(&hist[dst[e] >> BSH], 1);
  }
  __syncthreads();
  int v = (t < NB) ? hist[t] : 0;
  if (t < 128) sc[t] = v;
  __syncthreads();
  int x = v;
  for (int ofs = 1; ofs < 128; ofs <<= 1) {
    int y = (t >= ofs && t < 128) ? sc[t - ofs] : 0;
    __syncthreads();
    if (t < 128) { x += y; sc[t] = x; }
    __syncthreads();
  }
  if (t < NB) {
    int st = x - v;
    start[t] = st;
    cur[t] = st;
    gbase[t] = atomicAdd(&bcur[t], hist[t]);
  }
  __syncthreads();
#pragma unroll
  for (int k = 0; k < 8; k++) {
    int e = base + t + k * 512;
    if (e < N_EDGES) {
      int d = dst[e];
      int b = d >> BSH;
      int lp = atomicAdd(&cur[b], 1);
      stage[lp] = make_int2((src[e] << 16) | d, __float_as_int(ew[e]));
    }
  }
  __syncthreads();
  int nedge = min(CT, N_EDGES - base);
  for (int i = t; i < nedge; i += 512) {
    int2 e = stage[i];
    int b = (e.x & 0xffff) >> BSH;
    part[(size_t)b * CAP + gbase[b] + (i - start[b])] = e;
  }
}

// ---------------------------------------------------------------------------
// Per-bucket fine sort -> offs[n]=(beg,end) + dst-sorted packed edata
// (4B: (src<<16)|bf16(w)).
// ---------------------------------------------------------------------------
__launch_bounds__(512)
__global__ void fine_kernel(const int* __restrict__ bcur,
                            const int2* __restrict__ part,
                            int2* __restrict__ offs,
                            unsigned int* __restrict__ edata) {
  __shared__ int nh[512];
  __shared__ int sc[512];
  int t = threadIdx.x;
  int b = blockIdx.x;
  int base = b * CAP;
  int cnt = bcur[b];
  int nb = b << BSH;
  nh[t] = 0;
  __syncthreads();
  for (int i = t; i < cnt; i += 512) {
    int d = part[base + i].x & 0xffff;
    atomicAdd(&nh[d - nb], 1);
  }
  __syncthreads();
  int v = nh[t];
  sc[t] = v;
  __syncthreads();
  int x = v;
  for (int ofs = 1; ofs < 512; ofs <<= 1) {
    int y = (t >= ofs) ? sc[t - ofs] : 0;
    __syncthreads();
    x += y;
    sc[t] = x;
    __syncthreads();
  }
  int beg = base + (x - v);
  offs[nb + t] = make_int2(beg, beg + v);
  nh[t] = beg;
  __syncthreads();
  for (int i = t; i < cnt; i += 512) {
    int2 e = part[base + i];
    int d = e.x & 0xffff;
    int pos = atomicAdd(&nh[d - nb], 1);
    edata[pos] = (unsigned)(e.x & 0xffff0000) | (unsigned)f2bf(__int_as_float(e.y));
  }
}

// ---------------------------------------------------------------------------
// FUSED gather1 + GEMM2. Phase 1: each wave gathers 16 rows as 8 DUAL-ROW
// iterations (rows r and r+8 interleaved -> 2x loads in flight, latency of
// one row hidden behind the other's FMAs). Phase 2: K=128 MFMA, B from WcT.
// ---------------------------------------------------------------------------
__launch_bounds__(256)
__global__ void g1gemm2_kernel(const unsigned short* __restrict__ XWb,
                               const int2* __restrict__ offs,
                               const unsigned int* __restrict__ edata,
                               const float* __restrict__ b1,
                               const unsigned short* __restrict__ WcT,
                               unsigned short* __restrict__ Tb) {
  __shared__ short A_lds[64][136];  // 128 cols + 8 pad
  const int t = threadIdx.x;
  const int lane = t & 63;
  const int wave = t >> 6;
  const int row0 = blockIdx.x * 64;
  const int l15 = lane & 15, quad = lane >> 4;

  float bb[8];
#pragma unroll
  for (int k = 0; k < 8; k++) bb[k] = b1[l15 * 8 + k];

  for (int rr = 0; rr < 8; rr++) {
    int rA = wave * 16 + rr;
    int rB = rA + 8;
    int gA = row0 + rA, gB = row0 + rB;
    float accA[8], accB[8];
#pragma unroll
    for (int k = 0; k < 8; k++) { accA[k] = 0.f; accB[k] = 0.f; }
    int jA = 0, eA = 0, jB = 0, eB = 0;
    if (gA < N_NODES) { int2 o = offs[gA]; jA = o.x + quad; eA = o.y; }
    if (gB < N_NODES) { int2 o = offs[gB]; jB = o.x + quad; eB = o.y; }
    // interleaved main: both rows 2-deep -> 4 row loads in flight per quad
    while (jA + 4 < eA && jB + 4 < eB) {
      unsigned a0 = edata[jA], a1 = edata[jA + 4];
      unsigned b0 = edata[jB], b1e = edata[jB + 4];
      ushort8v ra0 = *(const ushort8v*)(XWb + (size_t)(a0 >> 16) * NHID + l15 * 8);
      ushort8v ra1 = *(const ushort8v*)(XWb + (size_t)(a1 >> 16) * NHID + l15 * 8);
      ushort8v rb0 = *(const ushort8v*)(XWb + (size_t)(b0 >> 16) * NHID + l15 * 8);
      ushort8v rb1 = *(const ushort8v*)(XWb + (size_t)(b1e >> 16) * NHID + l15 * 8);
      float wa0 = bf2f((unsigned short)(a0 & 0xffffu));
      float wa1 = bf2f((unsigned short)(a1 & 0xffffu));
      float wb0 = bf2f((unsigned short)(b0 & 0xffffu));
      float wb1 = bf2f((unsigned short)(b1e & 0xffffu));
#pragma unroll
      for (int k = 0; k < 8; k++) accA[k] += bf2f(ra0[k]) * wa0;
#pragma unroll
      for (int k = 0; k < 8; k++) accA[k] += bf2f(ra1[k]) * wa1;
#pragma unroll
      for (int k = 0; k < 8; k++) accB[k] += bf2f(rb0[k]) * wb0;
#pragma unroll
      for (int k = 0; k < 8; k++) accB[k] += bf2f(rb1[k]) * wb1;
      jA += 8; jB += 8;
    }
    // drain A
    for (; jA + 4 < eA; jA += 8) {
      unsigned a0 = edata[jA], a1 = edata[jA + 4];
      ushort8v ra0 = *(const ushort8v*)(XWb + (size_t)(a0 >> 16) * NHID + l15 * 8);
      ushort8v ra1 = *(const ushort8v*)(XWb + (size_t)(a1 >> 16) * NHID + l15 * 8);
      float wa0 = bf2f((unsigned short)(a0 & 0xffffu));
      float wa1 = bf2f((unsigned short)(a1 & 0xffffu));
#pragma unroll
      for (int k = 0; k < 8; k++) accA[k] += bf2f(ra0[k]) * wa0;
#pragma unroll
      for (int k = 0; k < 8; k++) accA[k] += bf2f(ra1[k]) * wa1;
    }
    if (jA < eA) {
      unsigned a0 = edata[jA];
      ushort8v ra0 = *(const ushort8v*)(XWb + (size_t)(a0 >> 16) * NHID + l15 * 8);
      float wa0 = bf2f((unsigned short)(a0 & 0xffffu));
#pragma unroll
      for (int k = 0; k < 8; k++) accA[k] += bf2f(ra0[k]) * wa0;
    }
    // drain B
    for (; jB + 4 < eB; jB += 8) {
      unsigned b0 = edata[jB], b1e = edata[jB + 4];
      ushort8v rb0 = *(const ushort8v*)(XWb + (size_t)(b0 >> 16) * NHID + l15 * 8);
      ushort8v rb1 = *(const ushort8v*)(XWb + (size_t)(b1e >> 16) * NHID + l15 * 8);
      float wb0 = bf2f((unsigned short)(b0 & 0xffffu));
      float wb1 = bf2f((unsigned short)(b1e & 0xffffu));
#pragma unroll
      for (int k = 0; k < 8; k++) accB[k] += bf2f(rb0[k]) * wb0;
#pragma unroll
      for (int k = 0; k < 8; k++) accB[k] += bf2f(rb1[k]) * wb1;
    }
    if (jB < eB) {
      unsigned b0 = edata[jB];
      ushort8v rb0 = *(const ushort8v*)(XWb + (size_t)(b0 >> 16) * NHID + l15 * 8);
      float wb0 = bf2f((unsigned short)(b0 & 0xffffu));
#pragma unroll
      for (int k = 0; k < 8; k++) accB[k] += bf2f(rb0[k]) * wb0;
    }
#pragma unroll
    for (int k = 0; k < 8; k++) {
      accA[k] += __shfl_down(accA[k], 32, 64);
      accA[k] += __shfl_down(accA[k], 16, 64);
      accB[k] += __shfl_down(accB[k], 32, 64);
      accB[k] += __shfl_down(accB[k], 16, 64);
    }
    if (lane < 16) {
      short8v sA, sB;
#pragma unroll
      for (int k = 0; k < 8; k++) {
        sA[k] = (short)f2bf(fmaxf(accA[k] + bb[k], 0.f));
        sB[k] = (short)f2bf(fmaxf(accB[k] + bb[k], 0.f));
      }
      *(short8v*)&A_lds[rA][l15 * 8] = sA;
      *(short8v*)&A_lds[rB][l15 * 8] = sB;
    }
  }
  __syncthreads();

  // phase 2: MFMA over K=128
  f32x4 acc2[4][2];
#pragma unroll
  for (int i = 0; i < 4; i++)
#pragma unroll
    for (int j = 0; j < 2; j++) acc2[i][j] = (f32x4){0.f, 0.f, 0.f, 0.f};

#pragma unroll
  for (int k0 = 0; k0 < NHID; k0 += 32) {
    bf16x8 a[4], b[2];
#pragma unroll
    for (int mt = 0; mt < 4; mt++)
      a[mt] = *(const bf16x8*)&A_lds[mt * 16 + l15][k0 + quad * 8];
#pragma unroll
    for (int nt = 0; nt < 2; nt++) {
      int n = wave * 32 + nt * 16 + l15;
      b[nt] = *(const bf16x8*)(WcT + (size_t)n * NHID + k0 + quad * 8);
    }
#pragma unroll
    for (int mt = 0; mt < 4; mt++)
#pragma unroll
      for (int nt = 0; nt < 2; nt++)
        acc2[mt][nt] = __builtin_amdgcn_mfma_f32_16x16x32_bf16(a[mt], b[nt], acc2[mt][nt], 0, 0, 0);
  }
#pragma unroll
  for (int mt = 0; mt < 4; mt++) {
#pragma unroll
    for (int reg = 0; reg < 4; reg++) {
      int gr = row0 + mt * 16 + quad * 4 + reg;
      if (gr < N_NODES) {
#pragma unroll
        for (int nt = 0; nt < 2; nt++) {
          int gc = wave * 32 + nt * 16 + l15;
          Tb[(size_t)gr * NHID + gc] = f2bf(acc2[mt][nt][reg]);
        }
      }
    }
  }
}

// ---------------------------------------------------------------------------
// Gather 2: one wave per TWO nodes (interleaved, 2-deep each -> 4 loads in
// flight per quad). out_mu = bmu + sum Tb[src][0:64]*w ; out_lv cols 64:128.
// ---------------------------------------------------------------------------
__launch_bounds__(256)
__global__ void gather2_kernel(const unsigned short* __restrict__ Tb,
                               const int2* __restrict__ offs,
                               const unsigned int* __restrict__ edata,
                               const float* __restrict__ bmu,
                               const float* __restrict__ blv,
                               float* __restrict__ out) {
  int wv = (int)((blockIdx.x * blockDim.x + threadIdx.x) >> 6);
  int gA = wv * 2, gB = wv * 2 + 1;
  if (gA >= N_NODES) return;
  int lane = threadIdx.x & 63;
  int quad = lane >> 4;
  int c8 = lane & 15;
  float accA[8], accB[8];
#pragma unroll
  for (int k = 0; k < 8; k++) { accA[k] = 0.f; accB[k] = 0.f; }
  int jA = 0, eA = 0, jB = 0, eB = 0;
  { int2 o = offs[gA]; jA = o.x + quad; eA = o.y; }
  if (gB < N_NODES) { int2 o = offs[gB]; jB = o.x + quad; eB = o.y; }
  while (jA + 4 < eA && jB + 4 < eB) {
    unsigned a0 = edata[jA], a1 = edata[jA + 4];
    unsigned b0 = edata[jB], b1e = edata[jB + 4];
    ushort8v ra0 = *(const ushort8v*)(Tb + (size_t)(a0 >> 16) * NHID + c8 * 8);
    ushort8v ra1 = *(const ushort8v*)(Tb + (size_t)(a1 >> 16) * NHID + c8 * 8);
    ushort8v rb0 = *(const ushort8v*)(Tb + (size_t)(b0 >> 16) * NHID + c8 * 8);
    ushort8v rb1 = *(const ushort8v*)(Tb + (size_t)(b1e >> 16) * NHID + c8 * 8);
    float wa0 = bf2f((unsigned short)(a0 & 0xffffu));
    float wa1 = bf2f((unsigned short)(a1 & 0xffffu));
    float wb0 = bf2f((unsigned short)(b0 & 0xffffu));
    float wb1 = bf2f((unsigned short)(b1e & 0xffffu));
#pragma unroll
    for (int k = 0; k < 8; k++) accA[k] += bf2f(ra0[k]) * wa0;
#pragma unroll
    for (int k = 0; k < 8; k++) accA[k] += bf2f(ra1[k]) * wa1;
#pragma unroll
    for (int k = 0; k < 8; k++) accB[k] += bf2f(rb0[k]) * wb0;
#pragma unroll
    for (int k = 0; k < 8; k++) accB[k] += bf2f(rb1[k]) * wb1;
    jA += 8; jB += 8;
  }
  for (; jA + 4 < eA; jA += 8) {
    unsigned a0 = edata[jA], a1 = edata[jA + 4];
    ushort8v ra0 = *(const ushort8v*)(Tb + (size_t)(a0 >> 16) * NHID + c8 * 8);
    ushort8v ra1 = *(const ushort8v*)(Tb + (size_t)(a1 >> 16) * NHID + c8 * 8);
    float wa0 = bf2f((unsigned short)(a0 & 0xffffu));
    float wa1 = bf2f((unsigned short)(a1 & 0xffffu));
#pragma unroll
    for (int k = 0; k < 8; k++) accA[k] += bf2f(ra0[k]) * wa0;
#pragma unroll
    for (int k = 0; k < 8; k++) accA[k] += bf2f(ra1[k]) * wa1;
  }
  if (jA < eA) {
    unsigned a0 = edata[jA];
    ushort8v ra0 = *(const ushort8v*)(Tb + (size_t)(a0 >> 16) * NHID + c8 * 8);
    float wa0 = bf2f((unsigned short)(a0 & 0xffffu));
#pragma unroll
    for (int k = 0; k < 8; k++) accA[k] += bf2f(ra0[k]) * wa0;
  }
  for (; jB + 4 < eB; jB += 8) {
    unsigned b0 = edata[jB], b1e = edata[jB + 4];
    ushort8v rb0 = *(const ushort8v*)(Tb + (size_t)(b0 >> 16) * NHID + c8 * 8);
    ushort8v rb1 = *(const ushort8v*)(Tb + (size_t)(b1e >> 16) * NHID + c8 * 8);
    float wb0 = bf2f((unsigned short)(b0 & 0xffffu));
    float wb1 = bf2f((unsigned short)(b1e & 0xffffu));
#pragma unroll
    for (int k = 0; k < 8; k++) accB[k] += bf2f(rb0[k]) * wb0;
#pragma unroll
    for (int k = 0; k < 8; k++) accB[k] += bf2f(rb1[k]) * wb1;
  }
  if (jB < eB) {
    unsigned b0 = edata[jB];
    ushort8v rb0 = *(const ushort8v*)(Tb + (size_t)(b0 >> 16) * NHID + c8 * 8);
    float wb0 = bf2f((unsigned short)(b0 & 0xffffu));
#pragma unroll
    for (int k = 0; k < 8; k++) accB[k] += bf2f(rb0[k]) * wb0;
  }
#pragma unroll
  for (int k = 0; k < 8; k++) {
    accA[k] += __shfl_down(accA[k], 32, 64);
    accA[k] += __shfl_down(accA[k], 16, 64);
    accB[k] += __shfl_down(accB[k], 32, 64);
    accB[k] += __shfl_down(accB[k], 16, 64);
  }
  if (lane < 8) {
    const float* bp = bmu + c8 * 8;
    float4 b0 = *(const float4*)bp;
    float4 b1v = *(const float4*)(bp + 4);
    float* op = out + (size_t)gA * LATENT + c8 * 8;
    float4 o0, o1;
    o0.x = accA[0] + b0.x; o0.y = accA[1] + b0.y;
    o0.z = accA[2] + b0.z; o0.w = accA[3] + b0.w;
    o1.x = accA[4] + b1v.x; o1.y = accA[5] + b1v.y;
    o1.z = accA[6] + b1v.z; o1.w = accA[7] + b1v.w;
    *(float4*)op = o0;
    *(float4*)(op + 4) = o1;
    if (gB < N_NODES) {
      float* opB = out + (size_t)gB * LATENT + c8 * 8;
      float4 p0, p1;
      p0.x = accB[0] + b0.x; p0.y = accB[1] + b0.y;
      p0.z = accB[2] + b0.z; p0.w = accB[3] + b0.w;
      p1.x = accB[4] + b1v.x; p1.y = accB[5] + b1v.y;
      p1.z = accB[6] + b1v.z; p1.w = accB[7] + b1v.w;
      *(float4*)opB = p0;
      *(float4*)(opB + 4) = p1;
    }
  } else if (lane < 16) {
    int c = c8 - 8;
    const float* bp = blv + c * 8;
    float4 b0 = *(const float4*)bp;
    float4 b1v = *(const float4*)(bp + 4);
    float* op = out + (size_t)N_NODES * LATENT + (size_t)gA * LATENT + c * 8;
    float4 o0, o1;
    o0.x = accA[0] + b0.x; o0.y = accA[1] + b0.y;
    o0.z = accA[2] + b0.z; o0.w = accA[3] + b0.w;
    o1.x = accA[4] + b1v.x; o1.y = accA[5] + b1v.y;
    o1.z = accA[6] + b1v.z; o1.w = accA[7] + b1v.w;
    *(float4*)op = o0;
    *(float4*)(op + 4) = o1;
    if (gB < N_NODES) {
      float* opB = out + (size_t)N_NODES * LATENT + (size_t)gB * LATENT + c * 8;
      float4 p0, p1;
      p0.x = accB[0] + b0.x; p0.y = accB[1] + b0.y;
      p0.z = accB[2] + b0.z; p0.w = accB[3] + b0.w;
      p1.x = accB[4] + b1v.x; p1.y = accB[5] + b1v.y;
      p1.z = accB[6] + b1v.z; p1.w = accB[7] + b1v.w;
      *(float4*)opB = p0;
      *(float4*)(opB + 4) = p1;
    }
  }
}

extern "C" void kernel_launch(void* const* d_in, const int* in_sizes, int n_in,
                              void* d_out, int out_size, void* d_ws, size_t ws_size,
                              hipStream_t stream) {
  const float* x   = (const float*)d_in[0];
  const int*   src = (const int*)d_in[1];
  const int*   dst = (const int*)d_in[2];
  const float* ew  = (const float*)d_in[3];
  const float* W1  = (const float*)d_in[4];
  const float* b1  = (const float*)d_in[5];
  const float* Wmu = (const float*)d_in[6];
  const float* bmu = (const float*)d_in[7];
  const float* Wlv = (const float*)d_in[8];
  const float* blv = (const float*)d_in[9];
  float* out = (float*)d_out;

  unsigned short* XWb = (unsigned short*)d_ws;             // 12.8 MB
  unsigned short* Tbb = XWb + (size_t)N_NODES * NHID;      // 12.8 MB
  int2* part = (int2*)(Tbb + (size_t)N_NODES * NHID);      // 7.0 MB
  unsigned int* edata = (unsigned int*)(part + (size_t)NB * CAP);  // 3.5 MB
  int2* offs = (int2*)(edata + (size_t)NB * CAP);          // 401 KB
  int* bcur  = (int*)(offs + 50176);                       // 128 ints
  unsigned short* W1T = (unsigned short*)(bcur + 128);     // 64 KB
  unsigned short* WcT = W1T + 128 * NFEAT;                 // 32 KB

  dim3 blk(256);
  int gemm_grid = (N_NODES + 63) / 64;              // 782
  int wave_grid2 = ((N_NODES + 1) / 2 * 64 + 255) / 256;  // 6250

  prep_w_kernel<<<257, blk, 0, stream>>>(W1, Wmu, Wlv, W1T, WcT, bcur);
  gemm1_kernel<<<gemm_grid, blk, 0, stream>>>(x, W1T, XWb);
  coarse_part_kernel<<<CBLK, dim3(512), 0, stream>>>(src, dst, ew, bcur, part);
  fine_kernel<<<NB, dim3(512), 0, stream>>>(bcur, part, offs, edata);
  g1gemm2_kernel<<<gemm_grid, blk, 0, stream>>>(XWb, offs, edata, b1, WcT, Tbb);
  gather2_kernel<<<wave_grid2, blk, 0, stream>>>(Tbb, offs, edata, bmu, blv, out);
}